// Round 15
// baseline (909.817 us; speedup 1.0000x reference)
//
#include <hip/hip_runtime.h>
#include <math.h>
#include <stdint.h>

#define NLEV 5
#define PPT 17616  // sum over levels of 4*(g+2)^2
#define HPX 320    // staged halo window (max needed span <= 306)

typedef __attribute__((ext_vector_type(8))) __bf16 bf16x8;
typedef __attribute__((ext_vector_type(4))) float f32x4;
typedef unsigned int u32;
typedef unsigned short u16;

#define MFMA16 __builtin_amdgcn_mfma_f32_16x16x32_bf16

__device__ __forceinline__ u32 f2bf(float f) {
  u32 u = __builtin_bit_cast(u32, f);
  return (u + 0x7FFFu + ((u >> 16) & 1u)) >> 16;
}
__device__ __forceinline__ void split2(float v, u32& hi, u32& lo) {
  hi = f2bf(v);
  lo = f2bf(v - __builtin_bit_cast(float, hi << 16));
}
__device__ __forceinline__ float bf2f(u32 bits16) {
  return __builtin_bit_cast(float, bits16 << 16);
}

// Activation layouts:
//  smpl tower: ONE bf16 plane  [granule][PPT px][8 ch]
//  cate tower: TWO bf16 planes (hi, lo), lo at +rows*PPT*8
//  bufA (build output): dual-plane (36 rows per plane); smpl reads hi only.
// Conv LDS stages ONLY the hi plane; cate's lo B-frags read from global (L2).

// ---------------------------------------------------------------------------
// Weight prep: fp32 [Cout][Cin][TAPS] -> MFMA A-frag layout, hi/lo planes.
// ks = cb*TAPS + tap. elem = ((((coT*KS+ks)*2+f)*2+wco)*64+lane)*8+j
// co = coT*64+wco*32+f*16+(lane&15); ci = cb*32+(lane>>4)*8+j
// ---------------------------------------------------------------------------
struct PrepDesc {
  const float* src[9];
  int Cin[9];
  int Cout[9];
  int CB[9];
  int TAPS[9];
  int nCoT[9];
  int dstOff[9];
};

__global__ __launch_bounds__(256) void prep_weights(PrepDesc pd, u16* __restrict__ wHi,
                                                    u16* __restrict__ wLo) {
  int cfg = blockIdx.y;
  int CB = pd.CB[cfg];
  int TAPS = pd.TAPS[cfg];
  int KS = CB * TAPS;
  int total = KS * 2048 * pd.nCoT[cfg];
  int didx = blockIdx.x * 256 + threadIdx.x;
  if (didx >= total) return;
  int j = didx & 7;
  int lane = (didx >> 3) & 63;
  int wco = (didx >> 9) & 1;
  int f = (didx >> 10) & 1;
  int rest = didx >> 11;
  int ks = rest % KS;
  int coT = rest / KS;
  int cb = ks / TAPS;
  int tap = ks - cb * TAPS;
  int ci = cb * 32 + ((lane >> 4) << 3) + j;
  int co = coT * 64 + wco * 32 + f * 16 + (lane & 15);
  float v = 0.f;
  if (ci < pd.Cin[cfg] && co < pd.Cout[cfg])
    v = pd.src[cfg][((size_t)co * pd.Cin[cfg] + ci) * TAPS + tap];
  u32 hi, lo;
  split2(v, hi, lo);
  wHi[pd.dstOff[cfg] + didx] = (u16)hi;
  wLo[pd.dstOff[cfg] + didx] = (u16)lo;
}

// ---------------------------------------------------------------------------
// halo ring zero: N granule-rows from base
// ---------------------------------------------------------------------------
struct ZeroDesc {
  int padOff[NLEV];
  int g[NLEV];
};

__global__ __launch_bounds__(256) void halo_zero(u16* __restrict__ base, ZeroDesc zd) {
  int px = blockIdx.x * 256 + threadIdx.x;
  if (px >= PPT) return;
  int l = 0;
#pragma unroll
  for (int i = 1; i < NLEV; i++)
    if (px >= zd.padOff[i]) l = i;
  int g = zd.g[l], gp2 = g + 2, hp2 = gp2 * gp2;
  int local = px - zd.padOff[l];
  int b = local / hp2;
  int rem = local - b * hp2;
  int yy = rem / gp2, xx = rem - yy * gp2;
  if (yy >= 1 && yy <= g && xx >= 1 && xx <= g) return;  // interior
  int r = blockIdx.y;
  uint4 z = {0u, 0u, 0u, 0u};
  *(uint4*)(base + ((size_t)r * PPT + px) * 8) = z;  // 8 u16 = 16B
}

// ---------------------------------------------------------------------------
// build: resize (optionally fused double resize) + coord ramps -> dual planes
// ---------------------------------------------------------------------------
struct BuildDesc {
  const float* src[NLEV];
  int H[NLEV];
  int mid[NLEV];
  int P[NLEV];
  int g[NLEV];
  int padOff[NLEV];
};

__device__ __forceinline__ float bsample(const float* __restrict__ pl, int H, int W,
                                         float fy, float fx) {
  int y0 = (int)floorf(fy);
  int y1 = min(y0 + 1, H - 1);
  float wy = fy - (float)y0;
  int x0 = (int)floorf(fx);
  int x1 = min(x0 + 1, W - 1);
  float wx = fx - (float)x0;
  const float* r0 = pl + (size_t)y0 * W;
  const float* r1 = pl + (size_t)y1 * W;
  float top = r0[x0] * (1.f - wx) + r0[x1] * wx;
  float bot = r1[x0] * (1.f - wx) + r1[x1] * wx;
  return top * (1.f - wy) + bot * wy;
}

__global__ __launch_bounds__(256) void build_all(BuildDesc bd, u16* __restrict__ dst) {
  int l = blockIdx.y;
  int P = bd.P[l];
  int g = bd.g[l];
  int total = 258 * P;
  int idx = blockIdx.x * 256 + threadIdx.x;
  if (idx >= total) return;
  int c = idx / P;
  int p = idx - c * P;
  int gg = g * g;
  int b = p / gg;
  int pr = p - b * gg;
  int i = pr / g;
  int j = pr - i * g;
  float val;
  if (c >= 256) {
    int tt = (c == 256) ? j : i;
    val = -1.f + 2.f * (float)tt / (float)(g - 1);
  } else {
    int H = bd.H[l], W = bd.H[l];
    int mid = bd.mid[l];
    const float* pl = bd.src[l] + ((size_t)b * 256 + c) * H * W;
    if (!mid) {
      float fy = (float)i * (float)(H - 1) / (float)(g - 1);
      float fx = (float)j * (float)(W - 1) / (float)(g - 1);
      val = bsample(pl, H, W, fy, fx);
    } else {
      int midh = mid, midw = mid;
      float fym = (float)i * (float)(midh - 1) / (float)(g - 1);
      float fxm = (float)j * (float)(midw - 1) / (float)(g - 1);
      int y0 = (int)floorf(fym);
      int y1 = min(y0 + 1, midh - 1);
      float wy = fym - (float)y0;
      int x0 = (int)floorf(fxm);
      int x1 = min(x0 + 1, midw - 1);
      float wx = fxm - (float)x0;
      float sy0 = (float)y0 * (float)(H - 1) / (float)(midh - 1);
      float sy1 = (float)y1 * (float)(H - 1) / (float)(midh - 1);
      float sx0 = (float)x0 * (float)(W - 1) / (float)(midw - 1);
      float sx1 = (float)x1 * (float)(W - 1) / (float)(midw - 1);
      float v00 = bsample(pl, H, W, sy0, sx0);
      float v01 = bsample(pl, H, W, sy0, sx1);
      float v10 = bsample(pl, H, W, sy1, sx0);
      float v11 = bsample(pl, H, W, sy1, sx1);
      float top = v00 * (1.f - wx) + v01 * wx;
      float bot = v10 * (1.f - wx) + v11 * wx;
      val = top * (1.f - wy) + bot * wy;
    }
  }
  int gp2 = g + 2;
  int hpos = bd.padOff[l] + b * gp2 * gp2 + (i + 1) * gp2 + (j + 1);
  u32 hi, lo;
  split2(val, hi, lo);
  size_t base = ((size_t)(c >> 3) * PPT + hpos) * 8 + (c & 7);
  dst[base] = (u16)hi;
  dst[(size_t)36 * PPT * 8 + base] = (u16)lo;
}

// ---------------------------------------------------------------------------
// MFMA conv 3x3 v9: v7 wave map (2co x 2px waves), hi-plane-only LDS halo
// (40KB -> 4 blocks/CU); cate lo-plane B-frags read from global (L2-hot).
//   smpl (tower 0): single-plane acts, 2-MFMA/MAC
//   cate (tower 1): dual-plane acts, 3-MFMA/MAC
// ---------------------------------------------------------------------------
struct ConvDesc {
  int tS[NLEV + 1];  // cumulative 128-px tiles
  int padOff[NLEV];
  int g[NLEV];
  int P[NLEV];
};

__global__ __launch_bounds__(256) void conv_mfma(
    const u16* __restrict__ inS, const u16* __restrict__ inC, int inCRows,
    const u16* __restrict__ wHiB, const u16* __restrict__ wLoB, int wOffS,
    int wOffC, const float* __restrict__ bS, const float* __restrict__ bC,
    u16* __restrict__ outS, u16* __restrict__ outC, ConvDesc d, int CBS, int CBC) {
  const int bid = blockIdx.x;
  const int xcd = bid & 7;
  const int i6 = bid >> 3;  // 0..127
  const int tower = i6 & 1;
  const int coT = (i6 >> 1) & 3;
  const int tile = xcd + (i6 >> 3) * 8;
  if (tile >= d.tS[NLEV]) return;

  const bool dual = (tower != 0);
  const u16* __restrict__ inHi = tower ? inC : inS;
  const u16* __restrict__ inLo = inHi + (size_t)inCRows * PPT * 8;  // dual only
  u16* __restrict__ outHi = tower ? outC : outS;
  u16* __restrict__ outLo = outHi + (size_t)32 * PPT * 8;  // dual only
  const u16* __restrict__ wH = wHiB + (tower ? wOffC : wOffS);
  const u16* __restrict__ wL = wLoB + (tower ? wOffC : wOffS);
  const float* __restrict__ bias = tower ? bC : bS;
  const int CB = tower ? CBC : CBS;
  const int KS = CB * 9;

  int l = 0;
#pragma unroll
  for (int i = 1; i < NLEV; i++)
    if (tile >= d.tS[i]) l = i;
  const int g = d.g[l];
  const int gp2 = g + 2, hp2 = gp2 * gp2, gg = g * g;
  const int padOff = d.padOff[l];
  const int Pl = d.P[l];
  const int ptile = (tile - d.tS[l]) * 128;

  const int t = threadIdx.x;
  const int lane = t & 63;
  const int wv = t >> 6;
  const int wco = wv & 1, wp = wv >> 1;
  const int kb = lane >> 4;
  const int sgr = wv;  // staging granule index (wave-uniform)

  int h0;
  {
    int b0 = ptile / gg, pr0 = ptile - b0 * gg;
    int y0 = pr0 / g, x0 = pr0 - y0 * g;
    h0 = padOff + b0 * hp2 + (y0 + 1) * gp2 + (x0 + 1) - gp2 - 1;
  }

  int hRel[4], ob[4];
  bool vst[4];
#pragma unroll
  for (int fi = 0; fi < 4; fi++) {
    int pb = ptile + wp * 64 + fi * 16;
    vst[fi] = pb < Pl;
    int pf = pb + (lane & 15);
    if (pf >= Pl) pf = Pl - 1;
    int b = pf / gg, pr = pf - b * gg;
    int y = pr / g, x = pr - y * g;
    int h = padOff + b * hp2 + (y + 1) * gp2 + (x + 1);
    hRel[fi] = h - h0;
    ob[fi] = h;
  }

  // [dbuf][granule][px][8ch] u16 -> 2*4*320*8*2B = 40960 B (hi plane only)
  __shared__ u16 halo[2 * 4 * HPX * 8];

  f32x4 acc[2][4];
#pragma unroll
  for (int c = 0; c < 2; c++)
#pragma unroll
    for (int fi = 0; fi < 4; fi++) acc[c][fi] = (f32x4){0.f, 0.f, 0.f, 0.f};

  const size_t wbase =
      (size_t)coT * KS * 2048 + (size_t)wco * 512 + (size_t)lane * 8;
  bf16x8 ah0 = *(const bf16x8*)(wH + wbase);
  bf16x8 ah1 = *(const bf16x8*)(wH + wbase + 1024);
  bf16x8 al0 = *(const bf16x8*)(wL + wbase);
  bf16x8 al1 = *(const bf16x8*)(wL + wbase + 1024);

#define STAGE(dbuf, cbn)                                                          \
  {                                                                               \
    const int gr_ = (cbn)*4 + sgr;                                                \
    const u16* ghi_ = inHi + ((size_t)gr_ * PPT + h0) * 8;                        \
    u16* lb_ = halo + (size_t)((dbuf)*4 + sgr) * (HPX * 8);                       \
    _Pragma("unroll") for (int i_ = 0; i_ < 5; i_++) {                            \
      __builtin_amdgcn_global_load_lds(                                           \
          (const __attribute__((address_space(1))) void*)(ghi_ +                  \
                                                          (size_t)(i_ * 64 + lane) * 8), \
          (__attribute__((address_space(3))) void*)(lb_ + i_ * 64 * 8), 16, 0, 0);\
    }                                                                             \
  }

  STAGE(0, 0);

  for (int cb = 0; cb < CB; ++cb) {
    const int cur = cb & 1;
    __syncthreads();  // vmcnt(0)+barrier: L(cb) landed (issued a tap-phase ago)
    if (cb + 1 < CB) STAGE(cur ^ 1, cb + 1);  // hidden under the 9-tap MFMA phase

    const u16* loBase =
        dual ? (inLo + ((size_t)(cb * 4 + kb) * PPT + h0) * 8) : (const u16*)0;

#pragma unroll
    for (int tap = 0; tap < 9; ++tap) {
      const int ks = cb * 9 + tap;
      bf16x8 ah0n, ah1n, al0n, al1n;
      const bool have = (ks + 1) < KS;
      if (have) {
        size_t wo = wbase + (size_t)(ks + 1) * 2048;
        ah0n = *(const bf16x8*)(wH + wo);
        ah1n = *(const bf16x8*)(wH + wo + 1024);
        al0n = *(const bf16x8*)(wL + wo);
        al1n = *(const bf16x8*)(wL + wo + 1024);
      }
      const int toff = (tap / 3 - 1) * gp2 + (tap % 3) - 1;
      const u16* kbase = halo + (size_t)(cur * 4 + kb) * (HPX * 8);

      // cate: fetch lo-plane B-frags from global (L2-hot) up front
      bf16x8 blv[4];
      if (dual) {
#pragma unroll
        for (int fi = 0; fi < 4; fi++)
          blv[fi] = *(const bf16x8*)(loBase + (size_t)(hRel[fi] + toff) * 8);
      }

#pragma unroll
      for (int fi = 0; fi < 4; fi++) {
        bf16x8 bh = *(const bf16x8*)(kbase + (hRel[fi] + toff) * 8);
        acc[0][fi] = MFMA16(ah0, bh, acc[0][fi], 0, 0, 0);
        acc[0][fi] = MFMA16(al0, bh, acc[0][fi], 0, 0, 0);
        acc[1][fi] = MFMA16(ah1, bh, acc[1][fi], 0, 0, 0);
        acc[1][fi] = MFMA16(al1, bh, acc[1][fi], 0, 0, 0);
        if (dual) {
          acc[0][fi] = MFMA16(ah0, blv[fi], acc[0][fi], 0, 0, 0);
          acc[1][fi] = MFMA16(ah1, blv[fi], acc[1][fi], 0, 0, 0);
        }
      }
      if (have) {
        ah0 = ah0n;
        ah1 = ah1n;
        al0 = al0n;
        al1 = al1n;
      }
    }
  }
#undef STAGE

  // epilogue: bias + relu + round/split + plane store(s)
  const int coBase = coT * 64 + wco * 32 + ((lane >> 4) << 2);
  float bAv[4], bBv[4];
#pragma unroll
  for (int i = 0; i < 4; i++) {
    bAv[i] = bias[coBase + i];
    bBv[i] = bias[coBase + 16 + i];
  }
  const size_t rowA = (size_t)(coBase >> 3) * PPT;
  const size_t rowB = (size_t)((coBase + 16) >> 3) * PPT;
  const int sub = coBase & 7;
#pragma unroll
  for (int fi = 0; fi < 4; fi++) {
    if (!vst[fi]) continue;
    if (!dual) {
      u32 h[4];
#pragma unroll
      for (int i = 0; i < 4; i++) h[i] = f2bf(fmaxf(acc[0][fi][i] + bAv[i], 0.f));
      uint2 hs = {h[0] | (h[1] << 16), h[2] | (h[3] << 16)};
      *(uint2*)(outHi + (rowA + ob[fi]) * 8 + sub) = hs;
#pragma unroll
      for (int i = 0; i < 4; i++) h[i] = f2bf(fmaxf(acc[1][fi][i] + bBv[i], 0.f));
      hs.x = h[0] | (h[1] << 16);
      hs.y = h[2] | (h[3] << 16);
      *(uint2*)(outHi + (rowB + ob[fi]) * 8 + sub) = hs;
    } else {
      u32 h[4], lo[4];
#pragma unroll
      for (int i = 0; i < 4; i++)
        split2(fmaxf(acc[0][fi][i] + bAv[i], 0.f), h[i], lo[i]);
      uint2 hs = {h[0] | (h[1] << 16), h[2] | (h[3] << 16)};
      uint2 ls = {lo[0] | (lo[1] << 16), lo[2] | (lo[3] << 16)};
      *(uint2*)(outHi + (rowA + ob[fi]) * 8 + sub) = hs;
      *(uint2*)(outLo + (rowA + ob[fi]) * 8 + sub) = ls;
#pragma unroll
      for (int i = 0; i < 4; i++)
        split2(fmaxf(acc[1][fi][i] + bBv[i], 0.f), h[i], lo[i]);
      hs.x = h[0] | (h[1] << 16);
      hs.y = h[2] | (h[3] << 16);
      ls.x = lo[0] | (lo[1] << 16);
      ls.y = lo[2] | (lo[3] << 16);
      *(uint2*)(outHi + (rowB + ob[fi]) * 8 + sub) = hs;
      *(uint2*)(outLo + (rowB + ob[fi]) * 8 + sub) = ls;
    }
  }
}

// ---------------------------------------------------------------------------
// smpl head: 1x1 conv via MFMA, single-plane acts, NHWC out.
// ---------------------------------------------------------------------------
struct HeadDesc {
  int tS64[NLEV + 1];
  int padOff[NLEV];
  int g[NLEV];
  int outOff[NLEV];
};

__global__ __launch_bounds__(256) void head1x1(
    const u16* __restrict__ actIn, const u16* __restrict__ wH,
    const u16* __restrict__ wL, const float* __restrict__ bias,
    const float* __restrict__ bias2, float* __restrict__ outB, HeadDesc d) {
  const int bx = blockIdx.x;
  const int coT = blockIdx.y;
  int l = 0;
#pragma unroll
  for (int i = 1; i < NLEV; i++)
    if (bx >= d.tS64[i]) l = i;
  const int g = d.g[l], gp2 = g + 2, hp2 = gp2 * gp2, gg = g * g;
  const int ptile = (bx - d.tS64[l]) * 64;
  const int t = threadIdx.x, lane = t & 63, wv = t >> 6;
  const int wco = wv & 1, wp = wv >> 1, kb = lane >> 4;

  int hp[2], pF[2];
#pragma unroll
  for (int fi = 0; fi < 2; fi++) {
    int pf = ptile + wp * 32 + fi * 16 + (lane & 15);
    pF[fi] = pf;
    int b = pf / gg, pr = pf - b * gg, y = pr / g, x = pr - y * g;
    hp[fi] = d.padOff[l] + b * hp2 + (y + 1) * gp2 + (x + 1);
  }
  f32x4 acc[2][2];
#pragma unroll
  for (int c = 0; c < 2; c++)
#pragma unroll
    for (int fi = 0; fi < 2; fi++) acc[c][fi] = (f32x4){0.f, 0.f, 0.f, 0.f};

  const size_t wbase = (size_t)coT * 8 * 2048 + (size_t)wco * 512 + (size_t)lane * 8;
  for (int cb = 0; cb < 8; ++cb) {
    size_t wo = wbase + (size_t)cb * 2048;
    bf16x8 ah0 = *(const bf16x8*)(wH + wo);
    bf16x8 ah1 = *(const bf16x8*)(wH + wo + 1024);
    bf16x8 al0 = *(const bf16x8*)(wL + wo);
    bf16x8 al1 = *(const bf16x8*)(wL + wo + 1024);
    const int gr = cb * 4 + kb;
#pragma unroll
    for (int fi = 0; fi < 2; fi++) {
      bf16x8 b = *(const bf16x8*)(actIn + ((size_t)gr * PPT + hp[fi]) * 8);
      acc[0][fi] = MFMA16(ah0, b, acc[0][fi], 0, 0, 0);
      acc[0][fi] = MFMA16(al0, b, acc[0][fi], 0, 0, 0);
      acc[1][fi] = MFMA16(ah1, b, acc[1][fi], 0, 0, 0);
      acc[1][fi] = MFMA16(al1, b, acc[1][fi], 0, 0, 0);
    }
  }
  const int coBase = coT * 64 + wco * 32 + ((lane >> 4) << 2);
#pragma unroll
  for (int c = 0; c < 2; c++)
#pragma unroll
    for (int fi = 0; fi < 2; fi++)
#pragma unroll
      for (int i = 0; i < 4; i++) {
        int co = coBase + c * 16 + i;
        if (co < 157)
          outB[d.outOff[l] + (size_t)pF[fi] * 157 + co] =
              acc[c][fi][i] + bias[co] + bias2[co];
      }
}

// ---------------------------------------------------------------------------
// cate head: 3x3 conv Cout=1 + sigmoid; dual-plane reads.
// ---------------------------------------------------------------------------
struct CHDesc {
  int tS64[NLEV + 1];
  int padOff[NLEV];
  int g[NLEV];
  int outOff[NLEV];
};

__global__ __launch_bounds__(256) void cate_head_all(
    const u16* __restrict__ inHi, const u16* __restrict__ inLo,
    const float* __restrict__ w, const float* __restrict__ bias,
    float* __restrict__ heat, CHDesc d) {
  int tile = blockIdx.x;
  int l = 0;
#pragma unroll
  for (int i = 1; i < NLEV; i++)
    if (tile >= d.tS64[i]) l = i;
  const int g = d.g[l];
  const int gp2 = g + 2, hp2 = gp2 * gp2, gg = g * g;
  const int t = threadIdx.x;
  const int ps = t & 63;
  const int cw = t >> 6;
  const int ptile = (tile - d.tS64[l]) * 64;
  int p = ptile + ps;
  int b = p / gg, pr = p - b * gg, y = pr / g, x = pr - y * g;
  const int hbase = d.padOff[l] + b * hp2 + (y + 1) * gp2 + (x + 1);

  __shared__ float ws[32][9][8];
  for (int i = t; i < 2304; i += 256) {
    int ci = i / 9, tap = i - ci * 9;
    ws[ci >> 3][tap][ci & 7] = w[i];
  }
  __syncthreads();

  float s = 0.f;
  for (int gr = cw; gr < 32; gr += 4) {
    const u16* ph = inHi + ((size_t)gr * PPT + hbase) * 8;
    const u16* pl = inLo + ((size_t)gr * PPT + hbase) * 8;
#pragma unroll
    for (int tap = 0; tap < 9; tap++) {
      const int toff = (tap / 3 - 1) * gp2 + (tap % 3) - 1;
      uint4 hq = *(const uint4*)(ph + (ptrdiff_t)toff * 8);
      uint4 lq = *(const uint4*)(pl + (ptrdiff_t)toff * 8);
      const float* wp = ws[gr][tap];
      s += (bf2f(hq.x & 0xFFFFu) + bf2f(lq.x & 0xFFFFu)) * wp[0] +
           (bf2f(hq.x >> 16) + bf2f(lq.x >> 16)) * wp[1] +
           (bf2f(hq.y & 0xFFFFu) + bf2f(lq.y & 0xFFFFu)) * wp[2] +
           (bf2f(hq.y >> 16) + bf2f(lq.y >> 16)) * wp[3] +
           (bf2f(hq.z & 0xFFFFu) + bf2f(lq.z & 0xFFFFu)) * wp[4] +
           (bf2f(hq.z >> 16) + bf2f(lq.z >> 16)) * wp[5] +
           (bf2f(hq.w & 0xFFFFu) + bf2f(lq.w & 0xFFFFu)) * wp[6] +
           (bf2f(hq.w >> 16) + bf2f(lq.w >> 16)) * wp[7];
    }
  }
  __shared__ float red[4][64];
  red[cw][ps] = s;
  __syncthreads();
  if (cw == 0) {
    float tot = bias[0] + red[0][ps] + red[1][ps] + red[2][ps] + red[3][ps];
    heat[d.outOff[l] + p] = 1.f / (1.f + expf(-tot));
  }
}

// points_nms * heat, flat heat in (cumP offsets), NHWC (C=1) out.
struct SmallDesc {
  int P[NLEV];
  int g[NLEV];
  int inOff[NLEV];
  int outOff[NLEV];
};

__global__ void nms_all(const float* __restrict__ heat, float* __restrict__ out,
                        SmallDesc d) {
  int l = blockIdx.y;
  int P = d.P[l], g = d.g[l];
  int gg = g * g;
  int p = blockIdx.x * 256 + threadIdx.x;
  if (p >= P) return;
  int pr = p % gg;
  int y = pr / g;
  int x = pr - y * g;
  const float* hb = heat + d.inOff[l];
  float c = hb[p], m = c;
  if (y > 0) {
    m = fmaxf(m, hb[p - g]);
    if (x > 0) m = fmaxf(m, hb[p - g - 1]);
  }
  if (x > 0) m = fmaxf(m, hb[p - 1]);
  out[d.outOff[l] + p] = (m == c) ? c : 0.f;
}

// ---------------------------------------------------------------------------
extern "C" void kernel_launch(void* const* d_in, const int* in_sizes, int n_in,
                              void* d_out, int out_size, void* d_ws, size_t ws_size,
                              hipStream_t stream) {
  const float* feat[5];
  for (int i = 0; i < 5; i++) feat[i] = (const float*)d_in[i];
  const float* smpl_w0 = (const float*)d_in[5];
  const float* smpl_b0 = (const float*)d_in[6];
  const float* smpl_w = (const float*)d_in[7];
  const float* smpl_b = (const float*)d_in[8];
  const float* cate_w0 = (const float*)d_in[9];
  const float* cate_b0 = (const float*)d_in[10];
  const float* cate_w = (const float*)d_in[11];
  const float* cate_b = (const float*)d_in[12];
  const float* cate_head_w = (const float*)d_in[13];
  const float* cate_head_b = (const float*)d_in[14];
  const float* smpl_head_w = (const float*)d_in[15];
  const float* smpl_head_b = (const float*)d_in[16];
  const float* smpl_init = (const float*)d_in[17];
  float* out = (float*)d_out;

  static const int GR[5] = {40, 36, 24, 16, 12};
  static const int SH[5] = {200, 100, 50, 25, 13};
  static const int MIDW[5] = {100, 0, 0, 0, 25};

  int P[5], cumP[6], tS64[6], tS128[6], padOff[5];
  cumP[0] = 0;
  tS64[0] = 0;
  tS128[0] = 0;
  int po = 0;
  for (int l = 0; l < 5; l++) {
    P[l] = 4 * GR[l] * GR[l];
    cumP[l + 1] = cumP[l] + P[l];
    tS64[l + 1] = tS64[l] + P[l] / 64;
    tS128[l + 1] = tS128[l] + (P[l] + 127) / 128;
    padOff[l] = po;
    po += 4 * (GR[l] + 2) * (GR[l] + 2);
  }

  int smpl_off[5], cate_off[5];
  {
    int off = 0;
    for (int l = 0; l < 5; l++) {
      smpl_off[l] = off;
      off += P[l] * 157;
    }
    for (int l = 0; l < 5; l++) {
      cate_off[l] = off;
      off += P[l];
    }
  }

  // workspace (u16 units):
  //   bufA dual (72 rows) | Bs (32) | Cs (32) | Bc dual (64) | Cc dual (64)
  u16* bufA = (u16*)d_ws;
  u16* bufBs = bufA + (size_t)72 * PPT * 8;
  u16* bufCs = bufBs + (size_t)32 * PPT * 8;
  u16* bufBc = bufCs + (size_t)32 * PPT * 8;
  u16* bufCc = bufBc + (size_t)64 * PPT * 8;
  float* heat = (float*)(bufCc + (size_t)64 * PPT * 8);
  u16* wHi = (u16*)(heat + 15488);

  // weight prep configs
  PrepDesc pd;
  const size_t LSTR = (size_t)256 * 256 * 9;
  pd.src[0] = smpl_w0;
  pd.src[1] = smpl_w;
  pd.src[2] = smpl_w + LSTR;
  pd.src[3] = smpl_w + 2 * LSTR;
  pd.src[4] = cate_w0;
  pd.src[5] = cate_w;
  pd.src[6] = cate_w + LSTR;
  pd.src[7] = cate_w + 2 * LSTR;
  pd.src[8] = smpl_head_w;
  for (int i = 0; i < 9; i++) {
    pd.Cin[i] = 256;
    pd.Cout[i] = 256;
    pd.CB[i] = 8;
    pd.TAPS[i] = 9;
    pd.nCoT[i] = 4;
  }
  pd.Cin[0] = 258;
  pd.CB[0] = 9;
  pd.Cout[8] = 157;
  pd.TAPS[8] = 1;
  pd.nCoT[8] = 3;
  size_t WTOT = 0;
  for (int i = 0; i < 9; i++) {
    pd.dstOff[i] = (int)WTOT;
    WTOT += (size_t)pd.CB[i] * pd.TAPS[i] * 2048 * pd.nCoT[i];
  }
  u16* wLo = wHi + WTOT;

  // zero bufA (both planes incl pad granules + rings); ring-zero tower buffers
  hipMemsetAsync(bufA, 0, (size_t)72 * PPT * 16, stream);
  ZeroDesc zd;
  for (int l = 0; l < 5; l++) {
    zd.padOff[l] = padOff[l];
    zd.g[l] = GR[l];
  }
  // 192 contiguous granule-rows: Bs(32) + Cs(32) + Bc(64) + Cc(64)
  hipLaunchKernelGGL(halo_zero, dim3((PPT + 255) / 256, 192), dim3(256), 0, stream,
                     bufBs, zd);

  hipLaunchKernelGGL(prep_weights, dim3(2592, 9), dim3(256), 0, stream, pd, wHi, wLo);

  // build inputs (dual-plane into bufA)
  BuildDesc bd;
  for (int l = 0; l < 5; l++) {
    bd.src[l] = feat[l];
    bd.H[l] = SH[l];
    bd.mid[l] = MIDW[l];
    bd.P[l] = P[l];
    bd.g[l] = GR[l];
    bd.padOff[l] = padOff[l];
  }
  hipLaunchKernelGGL(build_all, dim3((258 * P[0] + 255) / 256, 5), dim3(256), 0,
                     stream, bd, bufA);

  ConvDesc cd;
  HeadDesc hd;
  CHDesc chd;
  SmallDesc nd;
  for (int i = 0; i <= 5; i++) {
    cd.tS[i] = tS128[i];
    hd.tS64[i] = tS64[i];
    chd.tS64[i] = tS64[i];
  }
  for (int l = 0; l < 5; l++) {
    cd.padOff[l] = padOff[l];
    cd.g[l] = GR[l];
    cd.P[l] = P[l];
    hd.padOff[l] = padOff[l];
    hd.g[l] = GR[l];
    hd.outOff[l] = smpl_off[l];
    chd.padOff[l] = padOff[l];
    chd.g[l] = GR[l];
    chd.outOff[l] = cumP[l];
    nd.P[l] = P[l];
    nd.g[l] = GR[l];
    nd.inOff[l] = cumP[l];
    nd.outOff[l] = cate_off[l];
  }

  const int NT64 = tS64[5];   // 242
  const int CGRID = 8 * 128;  // 1024 blocks
  // merged tower conv stages (smpl single-plane, cate dual-plane)
  hipLaunchKernelGGL(conv_mfma, dim3(CGRID), dim3(256), 0, stream, bufA, bufA, 36,
                     wHi, wLo, pd.dstOff[0], pd.dstOff[4], smpl_b0, cate_b0, bufBs,
                     bufBc, cd, 9, 8);
  hipLaunchKernelGGL(conv_mfma, dim3(CGRID), dim3(256), 0, stream, bufBs, bufBc, 32,
                     wHi, wLo, pd.dstOff[1], pd.dstOff[5], smpl_b + 0, cate_b + 0,
                     bufCs, bufCc, cd, 8, 8);
  hipLaunchKernelGGL(conv_mfma, dim3(CGRID), dim3(256), 0, stream, bufCs, bufCc, 32,
                     wHi, wLo, pd.dstOff[2], pd.dstOff[6], smpl_b + 256,
                     cate_b + 256, bufBs, bufBc, cd, 8, 8);
  hipLaunchKernelGGL(conv_mfma, dim3(CGRID), dim3(256), 0, stream, bufBs, bufBc, 32,
                     wHi, wLo, pd.dstOff[3], pd.dstOff[7], smpl_b + 512,
                     cate_b + 512, bufCs, bufCc, cd, 8, 8);
  // heads
  hipLaunchKernelGGL(head1x1, dim3(NT64, 3), dim3(256), 0, stream, bufCs,
                     wHi + pd.dstOff[8], wLo + pd.dstOff[8], smpl_head_b, smpl_init,
                     out, hd);
  hipLaunchKernelGGL(cate_head_all, dim3(NT64), dim3(256), 0, stream, bufCc,
                     bufCc + (size_t)32 * PPT * 8, cate_head_w, cate_head_b, heat,
                     chd);
  hipLaunchKernelGGL(nms_all, dim3((P[0] + 255) / 256, 5), dim3(256), 0, stream,
                     heat, out, nd);
  (void)in_sizes;
  (void)n_in;
  (void)out_size;
  (void)ws_size;
}

// Round 16
// 499.494 us; speedup vs baseline: 1.8215x; 1.8215x over previous
//
#include <hip/hip_runtime.h>
#include <math.h>
#include <stdint.h>

#define NLEV 5
#define PPT 17616  // sum over levels of 4*(g+2)^2
#define HPX 320    // staged halo window (max needed span <= 306)

typedef __attribute__((ext_vector_type(8))) __bf16 bf16x8;
typedef __attribute__((ext_vector_type(4))) float f32x4;
typedef unsigned int u32;
typedef unsigned short u16;

#define MFMA16 __builtin_amdgcn_mfma_f32_16x16x32_bf16

__device__ __forceinline__ u32 f2bf(float f) {
  u32 u = __builtin_bit_cast(u32, f);
  return (u + 0x7FFFu + ((u >> 16) & 1u)) >> 16;
}
__device__ __forceinline__ void split2(float v, u32& hi, u32& lo) {
  hi = f2bf(v);
  lo = f2bf(v - __builtin_bit_cast(float, hi << 16));
}
__device__ __forceinline__ float bf2f(u32 bits16) {
  return __builtin_bit_cast(float, bits16 << 16);
}

// Activation layouts:
//  smpl tower: ONE bf16 plane  [granule][PPT px][8 ch]
//  cate tower: TWO bf16 planes (hi, lo), lo at +rows*PPT*8
//  bufA (build output): dual-plane (36 rows per plane); smpl reads hi only.

// ---------------------------------------------------------------------------
// Weight prep: fp32 [Cout][Cin][TAPS] -> MFMA A-frag layout, hi/lo planes.
// ks = cb*TAPS + tap. elem = ((((coT*KS+ks)*2+f)*2+wco)*64+lane)*8+j
// co = coT*64+wco*32+f*16+(lane&15); ci = cb*32+(lane>>4)*8+j
// ---------------------------------------------------------------------------
struct PrepDesc {
  const float* src[9];
  int Cin[9];
  int Cout[9];
  int CB[9];
  int TAPS[9];
  int nCoT[9];
  int dstOff[9];
};

__global__ __launch_bounds__(256) void prep_weights(PrepDesc pd, u16* __restrict__ wHi,
                                                    u16* __restrict__ wLo) {
  int cfg = blockIdx.y;
  int CB = pd.CB[cfg];
  int TAPS = pd.TAPS[cfg];
  int KS = CB * TAPS;
  int total = KS * 2048 * pd.nCoT[cfg];
  int didx = blockIdx.x * 256 + threadIdx.x;
  if (didx >= total) return;
  int j = didx & 7;
  int lane = (didx >> 3) & 63;
  int wco = (didx >> 9) & 1;
  int f = (didx >> 10) & 1;
  int rest = didx >> 11;
  int ks = rest % KS;
  int coT = rest / KS;
  int cb = ks / TAPS;
  int tap = ks - cb * TAPS;
  int ci = cb * 32 + ((lane >> 4) << 3) + j;
  int co = coT * 64 + wco * 32 + f * 16 + (lane & 15);
  float v = 0.f;
  if (ci < pd.Cin[cfg] && co < pd.Cout[cfg])
    v = pd.src[cfg][((size_t)co * pd.Cin[cfg] + ci) * TAPS + tap];
  u32 hi, lo;
  split2(v, hi, lo);
  wHi[pd.dstOff[cfg] + didx] = (u16)hi;
  wLo[pd.dstOff[cfg] + didx] = (u16)lo;
}

// ---------------------------------------------------------------------------
// halo ring zero: N granule-rows from base (covers Bs,Cs single + Bc,Cc dual)
// ---------------------------------------------------------------------------
struct ZeroDesc {
  int padOff[NLEV];
  int g[NLEV];
};

__global__ __launch_bounds__(256) void halo_zero(u16* __restrict__ base, ZeroDesc zd) {
  int px = blockIdx.x * 256 + threadIdx.x;
  if (px >= PPT) return;
  int l = 0;
#pragma unroll
  for (int i = 1; i < NLEV; i++)
    if (px >= zd.padOff[i]) l = i;
  int g = zd.g[l], gp2 = g + 2, hp2 = gp2 * gp2;
  int local = px - zd.padOff[l];
  int b = local / hp2;
  int rem = local - b * hp2;
  int yy = rem / gp2, xx = rem - yy * gp2;
  if (yy >= 1 && yy <= g && xx >= 1 && xx <= g) return;  // interior
  int r = blockIdx.y;
  uint4 z = {0u, 0u, 0u, 0u};
  *(uint4*)(base + ((size_t)r * PPT + px) * 8) = z;  // 8 u16 = 16B
}

// ---------------------------------------------------------------------------
// build: resize (optionally fused double resize) + coord ramps -> dual planes
// ---------------------------------------------------------------------------
struct BuildDesc {
  const float* src[NLEV];
  int H[NLEV];
  int mid[NLEV];
  int P[NLEV];
  int g[NLEV];
  int padOff[NLEV];
};

__device__ __forceinline__ float bsample(const float* __restrict__ pl, int H, int W,
                                         float fy, float fx) {
  int y0 = (int)floorf(fy);
  int y1 = min(y0 + 1, H - 1);
  float wy = fy - (float)y0;
  int x0 = (int)floorf(fx);
  int x1 = min(x0 + 1, W - 1);
  float wx = fx - (float)x0;
  const float* r0 = pl + (size_t)y0 * W;
  const float* r1 = pl + (size_t)y1 * W;
  float top = r0[x0] * (1.f - wx) + r0[x1] * wx;
  float bot = r1[x0] * (1.f - wx) + r1[x1] * wx;
  return top * (1.f - wy) + bot * wy;
}

__global__ __launch_bounds__(256) void build_all(BuildDesc bd, u16* __restrict__ dst) {
  int l = blockIdx.y;
  int P = bd.P[l];
  int g = bd.g[l];
  int total = 258 * P;
  int idx = blockIdx.x * 256 + threadIdx.x;
  if (idx >= total) return;
  int c = idx / P;
  int p = idx - c * P;
  int gg = g * g;
  int b = p / gg;
  int pr = p - b * gg;
  int i = pr / g;
  int j = pr - i * g;
  float val;
  if (c >= 256) {
    int tt = (c == 256) ? j : i;
    val = -1.f + 2.f * (float)tt / (float)(g - 1);
  } else {
    int H = bd.H[l], W = bd.H[l];
    int mid = bd.mid[l];
    const float* pl = bd.src[l] + ((size_t)b * 256 + c) * H * W;
    if (!mid) {
      float fy = (float)i * (float)(H - 1) / (float)(g - 1);
      float fx = (float)j * (float)(W - 1) / (float)(g - 1);
      val = bsample(pl, H, W, fy, fx);
    } else {
      int midh = mid, midw = mid;
      float fym = (float)i * (float)(midh - 1) / (float)(g - 1);
      float fxm = (float)j * (float)(midw - 1) / (float)(g - 1);
      int y0 = (int)floorf(fym);
      int y1 = min(y0 + 1, midh - 1);
      float wy = fym - (float)y0;
      int x0 = (int)floorf(fxm);
      int x1 = min(x0 + 1, midw - 1);
      float wx = fxm - (float)x0;
      float sy0 = (float)y0 * (float)(H - 1) / (float)(midh - 1);
      float sy1 = (float)y1 * (float)(H - 1) / (float)(midh - 1);
      float sx0 = (float)x0 * (float)(W - 1) / (float)(midw - 1);
      float sx1 = (float)x1 * (float)(W - 1) / (float)(midw - 1);
      float v00 = bsample(pl, H, W, sy0, sx0);
      float v01 = bsample(pl, H, W, sy0, sx1);
      float v10 = bsample(pl, H, W, sy1, sx0);
      float v11 = bsample(pl, H, W, sy1, sx1);
      float top = v00 * (1.f - wx) + v01 * wx;
      float bot = v10 * (1.f - wx) + v11 * wx;
      val = top * (1.f - wy) + bot * wy;
    }
  }
  int gp2 = g + 2;
  int hpos = bd.padOff[l] + b * gp2 * gp2 + (i + 1) * gp2 + (j + 1);
  u32 hi, lo;
  split2(val, hi, lo);
  size_t base = ((size_t)(c >> 3) * PPT + hpos) * 8 + (c & 7);
  dst[base] = (u16)hi;
  dst[(size_t)36 * PPT * 8 + base] = (u16)lo;
}

// ---------------------------------------------------------------------------
// MFMA conv 3x3 v7 (best known): merged towers, 128px x 64co tiles.
//   smpl (tower 0): single-plane acts, 2-MFMA/MAC
//   cate (tower 1): dual-plane acts, 3-MFMA/MAC
// DMA-staged double-buffered LDS halo via global_load_lds.
// ---------------------------------------------------------------------------
struct ConvDesc {
  int tS[NLEV + 1];  // cumulative 128-px tiles
  int padOff[NLEV];
  int g[NLEV];
  int P[NLEV];
};

__global__ __launch_bounds__(256) void conv_mfma(
    const u16* __restrict__ inS, const u16* __restrict__ inC, int inCRows,
    const u16* __restrict__ wHiB, const u16* __restrict__ wLoB, int wOffS,
    int wOffC, const float* __restrict__ bS, const float* __restrict__ bC,
    u16* __restrict__ outS, u16* __restrict__ outC, ConvDesc d, int CBS, int CBC) {
  const int bid = blockIdx.x;
  const int xcd = bid & 7;
  const int i6 = bid >> 3;  // 0..127
  const int tower = i6 & 1;
  const int coT = (i6 >> 1) & 3;
  const int tile = xcd + (i6 >> 3) * 8;
  if (tile >= d.tS[NLEV]) return;

  const bool dual = (tower != 0);
  const u16* __restrict__ inHi = tower ? inC : inS;
  const u16* __restrict__ inLo = inHi + (size_t)inCRows * PPT * 8;  // dual only
  u16* __restrict__ outHi = tower ? outC : outS;
  u16* __restrict__ outLo = outHi + (size_t)32 * PPT * 8;  // dual only
  const u16* __restrict__ wH = wHiB + (tower ? wOffC : wOffS);
  const u16* __restrict__ wL = wLoB + (tower ? wOffC : wOffS);
  const float* __restrict__ bias = tower ? bC : bS;
  const int CB = tower ? CBC : CBS;
  const int KS = CB * 9;

  int l = 0;
#pragma unroll
  for (int i = 1; i < NLEV; i++)
    if (tile >= d.tS[i]) l = i;
  const int g = d.g[l];
  const int gp2 = g + 2, hp2 = gp2 * gp2, gg = g * g;
  const int padOff = d.padOff[l];
  const int Pl = d.P[l];
  const int ptile = (tile - d.tS[l]) * 128;

  const int t = threadIdx.x;
  const int lane = t & 63;
  const int wv = t >> 6;
  const int wco = wv & 1, wp = wv >> 1;
  const int kb = lane >> 4;
  const int sgr = wv;  // staging granule index (wave-uniform)

  int h0;
  {
    int b0 = ptile / gg, pr0 = ptile - b0 * gg;
    int y0 = pr0 / g, x0 = pr0 - y0 * g;
    h0 = padOff + b0 * hp2 + (y0 + 1) * gp2 + (x0 + 1) - gp2 - 1;
  }

  int hRel[4], ob[4];
  bool vst[4];
#pragma unroll
  for (int fi = 0; fi < 4; fi++) {
    int pb = ptile + wp * 64 + fi * 16;
    vst[fi] = pb < Pl;
    int pf = pb + (lane & 15);
    if (pf >= Pl) pf = Pl - 1;
    int b = pf / gg, pr = pf - b * gg;
    int y = pr / g, x = pr - y * g;
    int h = padOff + b * hp2 + (y + 1) * gp2 + (x + 1);
    hRel[fi] = h - h0;
    ob[fi] = h;
  }

  // [dbuf][granule][plane][px][8ch] u16 -> 2*4*2*320*8*2B = 81920 B
  __shared__ u16 halo[2 * 4 * 2 * HPX * 8];

  f32x4 acc[2][4];
#pragma unroll
  for (int c = 0; c < 2; c++)
#pragma unroll
    for (int fi = 0; fi < 4; fi++) acc[c][fi] = (f32x4){0.f, 0.f, 0.f, 0.f};

  const size_t wbase =
      (size_t)coT * KS * 2048 + (size_t)wco * 512 + (size_t)lane * 8;
  bf16x8 ah0 = *(const bf16x8*)(wH + wbase);
  bf16x8 ah1 = *(const bf16x8*)(wH + wbase + 1024);
  bf16x8 al0 = *(const bf16x8*)(wL + wbase);
  bf16x8 al1 = *(const bf16x8*)(wL + wbase + 1024);

#define STAGE(dbuf, cbn)                                                          \
  {                                                                               \
    const int gr_ = (cbn)*4 + sgr;                                                \
    const u16* ghi_ = inHi + ((size_t)gr_ * PPT + h0) * 8;                        \
    u16* lb_ = halo + (size_t)(((dbuf)*4 + sgr) * 2) * (HPX * 8);                 \
    _Pragma("unroll") for (int i_ = 0; i_ < 5; i_++) {                            \
      __builtin_amdgcn_global_load_lds(                                           \
          (const __attribute__((address_space(1))) void*)(ghi_ +                  \
                                                          (size_t)(i_ * 64 + lane) * 8), \
          (__attribute__((address_space(3))) void*)(lb_ + i_ * 64 * 8), 16, 0, 0);\
    }                                                                             \
    if (dual) {                                                                   \
      const u16* glo_ = inLo + ((size_t)gr_ * PPT + h0) * 8;                      \
      _Pragma("unroll") for (int i_ = 0; i_ < 5; i_++) {                          \
        __builtin_amdgcn_global_load_lds(                                         \
            (const __attribute__((address_space(1))) void*)(glo_ +                \
                                                            (size_t)(i_ * 64 + lane) * 8), \
            (__attribute__((address_space(3))) void*)(lb_ + HPX * 8 +             \
                                                      i_ * 64 * 8),               \
            16, 0, 0);                                                            \
      }                                                                           \
    }                                                                             \
  }

  STAGE(0, 0);

  for (int cb = 0; cb < CB; ++cb) {
    const int cur = cb & 1;
    __syncthreads();  // vmcnt(0)+barrier: L(cb) landed (issued a tap-phase ago)
    if (cb + 1 < CB) STAGE(cur ^ 1, cb + 1);  // hidden under the 9-tap MFMA phase

#pragma unroll
    for (int tap = 0; tap < 9; ++tap) {
      const int ks = cb * 9 + tap;
      bf16x8 ah0n, ah1n, al0n, al1n;
      const bool have = (ks + 1) < KS;
      if (have) {
        size_t wo = wbase + (size_t)(ks + 1) * 2048;
        ah0n = *(const bf16x8*)(wH + wo);
        ah1n = *(const bf16x8*)(wH + wo + 1024);
        al0n = *(const bf16x8*)(wL + wo);
        al1n = *(const bf16x8*)(wL + wo + 1024);
      }
      const int toff = (tap / 3 - 1) * gp2 + (tap % 3) - 1;
      const u16* kbase = halo + (size_t)((cur * 4 + kb) * 2) * (HPX * 8);
#pragma unroll
      for (int fi = 0; fi < 4; fi++) {
        const u16* p0 = kbase + (hRel[fi] + toff) * 8;
        bf16x8 bh = *(const bf16x8*)p0;
        acc[0][fi] = MFMA16(ah0, bh, acc[0][fi], 0, 0, 0);
        acc[0][fi] = MFMA16(al0, bh, acc[0][fi], 0, 0, 0);
        acc[1][fi] = MFMA16(ah1, bh, acc[1][fi], 0, 0, 0);
        acc[1][fi] = MFMA16(al1, bh, acc[1][fi], 0, 0, 0);
        if (dual) {
          bf16x8 bl = *(const bf16x8*)(p0 + HPX * 8);
          acc[0][fi] = MFMA16(ah0, bl, acc[0][fi], 0, 0, 0);
          acc[1][fi] = MFMA16(ah1, bl, acc[1][fi], 0, 0, 0);
        }
      }
      if (have) {
        ah0 = ah0n;
        ah1 = ah1n;
        al0 = al0n;
        al1 = al1n;
      }
    }
  }
#undef STAGE

  // epilogue: bias + relu + round/split + plane store(s)
  const int coBase = coT * 64 + wco * 32 + ((lane >> 4) << 2);
  float bAv[4], bBv[4];
#pragma unroll
  for (int i = 0; i < 4; i++) {
    bAv[i] = bias[coBase + i];
    bBv[i] = bias[coBase + 16 + i];
  }
  const size_t rowA = (size_t)(coBase >> 3) * PPT;
  const size_t rowB = (size_t)((coBase + 16) >> 3) * PPT;
  const int sub = coBase & 7;
#pragma unroll
  for (int fi = 0; fi < 4; fi++) {
    if (!vst[fi]) continue;
    if (!dual) {
      u32 h[4];
#pragma unroll
      for (int i = 0; i < 4; i++) h[i] = f2bf(fmaxf(acc[0][fi][i] + bAv[i], 0.f));
      uint2 hs = {h[0] | (h[1] << 16), h[2] | (h[3] << 16)};
      *(uint2*)(outHi + (rowA + ob[fi]) * 8 + sub) = hs;
#pragma unroll
      for (int i = 0; i < 4; i++) h[i] = f2bf(fmaxf(acc[1][fi][i] + bBv[i], 0.f));
      hs.x = h[0] | (h[1] << 16);
      hs.y = h[2] | (h[3] << 16);
      *(uint2*)(outHi + (rowB + ob[fi]) * 8 + sub) = hs;
    } else {
      u32 h[4], lo[4];
#pragma unroll
      for (int i = 0; i < 4; i++)
        split2(fmaxf(acc[0][fi][i] + bAv[i], 0.f), h[i], lo[i]);
      uint2 hs = {h[0] | (h[1] << 16), h[2] | (h[3] << 16)};
      uint2 ls = {lo[0] | (lo[1] << 16), lo[2] | (lo[3] << 16)};
      *(uint2*)(outHi + (rowA + ob[fi]) * 8 + sub) = hs;
      *(uint2*)(outLo + (rowA + ob[fi]) * 8 + sub) = ls;
#pragma unroll
      for (int i = 0; i < 4; i++)
        split2(fmaxf(acc[1][fi][i] + bBv[i], 0.f), h[i], lo[i]);
      hs.x = h[0] | (h[1] << 16);
      hs.y = h[2] | (h[3] << 16);
      ls.x = lo[0] | (lo[1] << 16);
      ls.y = lo[2] | (lo[3] << 16);
      *(uint2*)(outHi + (rowB + ob[fi]) * 8 + sub) = hs;
      *(uint2*)(outLo + (rowB + ob[fi]) * 8 + sub) = ls;
    }
  }
}

// ---------------------------------------------------------------------------
// smpl head: 1x1 conv via MFMA, single-plane acts, NHWC out.
// ---------------------------------------------------------------------------
struct HeadDesc {
  int tS64[NLEV + 1];
  int padOff[NLEV];
  int g[NLEV];
  int outOff[NLEV];
};

__global__ __launch_bounds__(256) void head1x1(
    const u16* __restrict__ actIn, const u16* __restrict__ wH,
    const u16* __restrict__ wL, const float* __restrict__ bias,
    const float* __restrict__ bias2, float* __restrict__ outB, HeadDesc d) {
  const int bx = blockIdx.x;
  const int coT = blockIdx.y;
  int l = 0;
#pragma unroll
  for (int i = 1; i < NLEV; i++)
    if (bx >= d.tS64[i]) l = i;
  const int g = d.g[l], gp2 = g + 2, hp2 = gp2 * gp2, gg = g * g;
  const int ptile = (bx - d.tS64[l]) * 64;
  const int t = threadIdx.x, lane = t & 63, wv = t >> 6;
  const int wco = wv & 1, wp = wv >> 1, kb = lane >> 4;

  int hp[2], pF[2];
#pragma unroll
  for (int fi = 0; fi < 2; fi++) {
    int pf = ptile + wp * 32 + fi * 16 + (lane & 15);
    pF[fi] = pf;
    int b = pf / gg, pr = pf - b * gg, y = pr / g, x = pr - y * g;
    hp[fi] = d.padOff[l] + b * hp2 + (y + 1) * gp2 + (x + 1);
  }
  f32x4 acc[2][2];
#pragma unroll
  for (int c = 0; c < 2; c++)
#pragma unroll
    for (int fi = 0; fi < 2; fi++) acc[c][fi] = (f32x4){0.f, 0.f, 0.f, 0.f};

  const size_t wbase = (size_t)coT * 8 * 2048 + (size_t)wco * 512 + (size_t)lane * 8;
  for (int cb = 0; cb < 8; ++cb) {
    size_t wo = wbase + (size_t)cb * 2048;
    bf16x8 ah0 = *(const bf16x8*)(wH + wo);
    bf16x8 ah1 = *(const bf16x8*)(wH + wo + 1024);
    bf16x8 al0 = *(const bf16x8*)(wL + wo);
    bf16x8 al1 = *(const bf16x8*)(wL + wo + 1024);
    const int gr = cb * 4 + kb;
#pragma unroll
    for (int fi = 0; fi < 2; fi++) {
      bf16x8 b = *(const bf16x8*)(actIn + ((size_t)gr * PPT + hp[fi]) * 8);
      acc[0][fi] = MFMA16(ah0, b, acc[0][fi], 0, 0, 0);
      acc[0][fi] = MFMA16(al0, b, acc[0][fi], 0, 0, 0);
      acc[1][fi] = MFMA16(ah1, b, acc[1][fi], 0, 0, 0);
      acc[1][fi] = MFMA16(al1, b, acc[1][fi], 0, 0, 0);
    }
  }
  const int coBase = coT * 64 + wco * 32 + ((lane >> 4) << 2);
#pragma unroll
  for (int c = 0; c < 2; c++)
#pragma unroll
    for (int fi = 0; fi < 2; fi++)
#pragma unroll
      for (int i = 0; i < 4; i++) {
        int co = coBase + c * 16 + i;
        if (co < 157)
          outB[d.outOff[l] + (size_t)pF[fi] * 157 + co] =
              acc[c][fi][i] + bias[co] + bias2[co];
      }
}

// ---------------------------------------------------------------------------
// cate head: 3x3 conv Cout=1 + sigmoid; dual-plane reads.
// ---------------------------------------------------------------------------
struct CHDesc {
  int tS64[NLEV + 1];
  int padOff[NLEV];
  int g[NLEV];
  int outOff[NLEV];
};

__global__ __launch_bounds__(256) void cate_head_all(
    const u16* __restrict__ inHi, const u16* __restrict__ inLo,
    const float* __restrict__ w, const float* __restrict__ bias,
    float* __restrict__ heat, CHDesc d) {
  int tile = blockIdx.x;
  int l = 0;
#pragma unroll
  for (int i = 1; i < NLEV; i++)
    if (tile >= d.tS64[i]) l = i;
  const int g = d.g[l];
  const int gp2 = g + 2, hp2 = gp2 * gp2, gg = g * g;
  const int t = threadIdx.x;
  const int ps = t & 63;
  const int cw = t >> 6;
  const int ptile = (tile - d.tS64[l]) * 64;
  int p = ptile + ps;
  int b = p / gg, pr = p - b * gg, y = pr / g, x = pr - y * g;
  const int hbase = d.padOff[l] + b * hp2 + (y + 1) * gp2 + (x + 1);

  __shared__ float ws[32][9][8];
  for (int i = t; i < 2304; i += 256) {
    int ci = i / 9, tap = i - ci * 9;
    ws[ci >> 3][tap][ci & 7] = w[i];
  }
  __syncthreads();

  float s = 0.f;
  for (int gr = cw; gr < 32; gr += 4) {
    const u16* ph = inHi + ((size_t)gr * PPT + hbase) * 8;
    const u16* pl = inLo + ((size_t)gr * PPT + hbase) * 8;
#pragma unroll
    for (int tap = 0; tap < 9; tap++) {
      const int toff = (tap / 3 - 1) * gp2 + (tap % 3) - 1;
      uint4 hq = *(const uint4*)(ph + (ptrdiff_t)toff * 8);
      uint4 lq = *(const uint4*)(pl + (ptrdiff_t)toff * 8);
      const float* wp = ws[gr][tap];
      s += (bf2f(hq.x & 0xFFFFu) + bf2f(lq.x & 0xFFFFu)) * wp[0] +
           (bf2f(hq.x >> 16) + bf2f(lq.x >> 16)) * wp[1] +
           (bf2f(hq.y & 0xFFFFu) + bf2f(lq.y & 0xFFFFu)) * wp[2] +
           (bf2f(hq.y >> 16) + bf2f(lq.y >> 16)) * wp[3] +
           (bf2f(hq.z & 0xFFFFu) + bf2f(lq.z & 0xFFFFu)) * wp[4] +
           (bf2f(hq.z >> 16) + bf2f(lq.z >> 16)) * wp[5] +
           (bf2f(hq.w & 0xFFFFu) + bf2f(lq.w & 0xFFFFu)) * wp[6] +
           (bf2f(hq.w >> 16) + bf2f(lq.w >> 16)) * wp[7];
    }
  }
  __shared__ float red[4][64];
  red[cw][ps] = s;
  __syncthreads();
  if (cw == 0) {
    float tot = bias[0] + red[0][ps] + red[1][ps] + red[2][ps] + red[3][ps];
    heat[d.outOff[l] + p] = 1.f / (1.f + expf(-tot));
  }
}

// points_nms * heat, flat heat in (cumP offsets), NHWC (C=1) out.
struct SmallDesc {
  int P[NLEV];
  int g[NLEV];
  int inOff[NLEV];
  int outOff[NLEV];
};

__global__ void nms_all(const float* __restrict__ heat, float* __restrict__ out,
                        SmallDesc d) {
  int l = blockIdx.y;
  int P = d.P[l], g = d.g[l];
  int gg = g * g;
  int p = blockIdx.x * 256 + threadIdx.x;
  if (p >= P) return;
  int pr = p % gg;
  int y = pr / g;
  int x = pr - y * g;
  const float* hb = heat + d.inOff[l];
  float c = hb[p], m = c;
  if (y > 0) {
    m = fmaxf(m, hb[p - g]);
    if (x > 0) m = fmaxf(m, hb[p - g - 1]);
  }
  if (x > 0) m = fmaxf(m, hb[p - 1]);
  out[d.outOff[l] + p] = (m == c) ? c : 0.f;
}

// ---------------------------------------------------------------------------
extern "C" void kernel_launch(void* const* d_in, const int* in_sizes, int n_in,
                              void* d_out, int out_size, void* d_ws, size_t ws_size,
                              hipStream_t stream) {
  const float* feat[5];
  for (int i = 0; i < 5; i++) feat[i] = (const float*)d_in[i];
  const float* smpl_w0 = (const float*)d_in[5];
  const float* smpl_b0 = (const float*)d_in[6];
  const float* smpl_w = (const float*)d_in[7];
  const float* smpl_b = (const float*)d_in[8];
  const float* cate_w0 = (const float*)d_in[9];
  const float* cate_b0 = (const float*)d_in[10];
  const float* cate_w = (const float*)d_in[11];
  const float* cate_b = (const float*)d_in[12];
  const float* cate_head_w = (const float*)d_in[13];
  const float* cate_head_b = (const float*)d_in[14];
  const float* smpl_head_w = (const float*)d_in[15];
  const float* smpl_head_b = (const float*)d_in[16];
  const float* smpl_init = (const float*)d_in[17];
  float* out = (float*)d_out;

  static const int GR[5] = {40, 36, 24, 16, 12};
  static const int SH[5] = {200, 100, 50, 25, 13};
  static const int MIDW[5] = {100, 0, 0, 0, 25};

  int P[5], cumP[6], tS64[6], tS128[6], padOff[5];
  cumP[0] = 0;
  tS64[0] = 0;
  tS128[0] = 0;
  int po = 0;
  for (int l = 0; l < 5; l++) {
    P[l] = 4 * GR[l] * GR[l];
    cumP[l + 1] = cumP[l] + P[l];
    tS64[l + 1] = tS64[l] + P[l] / 64;
    tS128[l + 1] = tS128[l] + (P[l] + 127) / 128;
    padOff[l] = po;
    po += 4 * (GR[l] + 2) * (GR[l] + 2);
  }

  int smpl_off[5], cate_off[5];
  {
    int off = 0;
    for (int l = 0; l < 5; l++) {
      smpl_off[l] = off;
      off += P[l] * 157;
    }
    for (int l = 0; l < 5; l++) {
      cate_off[l] = off;
      off += P[l];
    }
  }

  // workspace (u16 units):
  //   bufA dual (72 rows) | Bs (32) | Cs (32) | Bc dual (64) | Cc dual (64)
  u16* bufA = (u16*)d_ws;
  u16* bufBs = bufA + (size_t)72 * PPT * 8;
  u16* bufCs = bufBs + (size_t)32 * PPT * 8;
  u16* bufBc = bufCs + (size_t)32 * PPT * 8;
  u16* bufCc = bufBc + (size_t)64 * PPT * 8;
  float* heat = (float*)(bufCc + (size_t)64 * PPT * 8);
  u16* wHi = (u16*)(heat + 15488);

  // weight prep configs
  PrepDesc pd;
  const size_t LSTR = (size_t)256 * 256 * 9;
  pd.src[0] = smpl_w0;
  pd.src[1] = smpl_w;
  pd.src[2] = smpl_w + LSTR;
  pd.src[3] = smpl_w + 2 * LSTR;
  pd.src[4] = cate_w0;
  pd.src[5] = cate_w;
  pd.src[6] = cate_w + LSTR;
  pd.src[7] = cate_w + 2 * LSTR;
  pd.src[8] = smpl_head_w;
  for (int i = 0; i < 9; i++) {
    pd.Cin[i] = 256;
    pd.Cout[i] = 256;
    pd.CB[i] = 8;
    pd.TAPS[i] = 9;
    pd.nCoT[i] = 4;
  }
  pd.Cin[0] = 258;
  pd.CB[0] = 9;
  pd.Cout[8] = 157;
  pd.TAPS[8] = 1;
  pd.nCoT[8] = 3;
  size_t WTOT = 0;
  for (int i = 0; i < 9; i++) {
    pd.dstOff[i] = (int)WTOT;
    WTOT += (size_t)pd.CB[i] * pd.TAPS[i] * 2048 * pd.nCoT[i];
  }
  u16* wLo = wHi + WTOT;

  // zero bufA (both planes incl pad granules + rings); ring-zero tower buffers
  hipMemsetAsync(bufA, 0, (size_t)72 * PPT * 16, stream);
  ZeroDesc zd;
  for (int l = 0; l < 5; l++) {
    zd.padOff[l] = padOff[l];
    zd.g[l] = GR[l];
  }
  // 192 contiguous granule-rows: Bs(32) + Cs(32) + Bc(64) + Cc(64)
  hipLaunchKernelGGL(halo_zero, dim3((PPT + 255) / 256, 192), dim3(256), 0, stream,
                     bufBs, zd);

  hipLaunchKernelGGL(prep_weights, dim3(2592, 9), dim3(256), 0, stream, pd, wHi, wLo);

  // build inputs (dual-plane into bufA)
  BuildDesc bd;
  for (int l = 0; l < 5; l++) {
    bd.src[l] = feat[l];
    bd.H[l] = SH[l];
    bd.mid[l] = MIDW[l];
    bd.P[l] = P[l];
    bd.g[l] = GR[l];
    bd.padOff[l] = padOff[l];
  }
  hipLaunchKernelGGL(build_all, dim3((258 * P[0] + 255) / 256, 5), dim3(256), 0,
                     stream, bd, bufA);

  ConvDesc cd;
  HeadDesc hd;
  CHDesc chd;
  SmallDesc nd;
  for (int i = 0; i <= 5; i++) {
    cd.tS[i] = tS128[i];
    hd.tS64[i] = tS64[i];
    chd.tS64[i] = tS64[i];
  }
  for (int l = 0; l < 5; l++) {
    cd.padOff[l] = padOff[l];
    cd.g[l] = GR[l];
    cd.P[l] = P[l];
    hd.padOff[l] = padOff[l];
    hd.g[l] = GR[l];
    hd.outOff[l] = smpl_off[l];
    chd.padOff[l] = padOff[l];
    chd.g[l] = GR[l];
    chd.outOff[l] = cumP[l];
    nd.P[l] = P[l];
    nd.g[l] = GR[l];
    nd.inOff[l] = cumP[l];
    nd.outOff[l] = cate_off[l];
  }

  const int NT64 = tS64[5];   // 242
  const int CGRID = 8 * 128;  // 1024 blocks
  // merged tower conv stages (smpl single-plane, cate dual-plane)
  hipLaunchKernelGGL(conv_mfma, dim3(CGRID), dim3(256), 0, stream, bufA, bufA, 36,
                     wHi, wLo, pd.dstOff[0], pd.dstOff[4], smpl_b0, cate_b0, bufBs,
                     bufBc, cd, 9, 8);
  hipLaunchKernelGGL(conv_mfma, dim3(CGRID), dim3(256), 0, stream, bufBs, bufBc, 32,
                     wHi, wLo, pd.dstOff[1], pd.dstOff[5], smpl_b + 0, cate_b + 0,
                     bufCs, bufCc, cd, 8, 8);
  hipLaunchKernelGGL(conv_mfma, dim3(CGRID), dim3(256), 0, stream, bufCs, bufCc, 32,
                     wHi, wLo, pd.dstOff[2], pd.dstOff[6], smpl_b + 256,
                     cate_b + 256, bufBs, bufBc, cd, 8, 8);
  hipLaunchKernelGGL(conv_mfma, dim3(CGRID), dim3(256), 0, stream, bufBs, bufBc, 32,
                     wHi, wLo, pd.dstOff[3], pd.dstOff[7], smpl_b + 512,
                     cate_b + 512, bufCs, bufCc, cd, 8, 8);
  // heads
  hipLaunchKernelGGL(head1x1, dim3(NT64, 3), dim3(256), 0, stream, bufCs,
                     wHi + pd.dstOff[8], wLo + pd.dstOff[8], smpl_head_b, smpl_init,
                     out, hd);
  hipLaunchKernelGGL(cate_head_all, dim3(NT64), dim3(256), 0, stream, bufCc,
                     bufCc + (size_t)32 * PPT * 8, cate_head_w, cate_head_b, heat,
                     chd);
  hipLaunchKernelGGL(nms_all, dim3((P[0] + 255) / 256, 5), dim3(256), 0, stream,
                     heat, out, nd);
  (void)in_sizes;
  (void)n_in;
  (void)out_size;
  (void)ws_size;
}

// Round 17
// 498.874 us; speedup vs baseline: 1.8237x; 1.0012x over previous
//
#include <hip/hip_runtime.h>
#include <math.h>
#include <stdint.h>

#define NLEV 5
#define PPT 17616  // sum over levels of 4*(g+2)^2
#define HPX 320    // staged halo window (max needed span <= 306)

typedef __attribute__((ext_vector_type(8))) __bf16 bf16x8;
typedef __attribute__((ext_vector_type(4))) float f32x4;
typedef unsigned int u32;
typedef unsigned short u16;

#define MFMA16 __builtin_amdgcn_mfma_f32_16x16x32_bf16

__device__ __forceinline__ u32 f2bf(float f) {
  u32 u = __builtin_bit_cast(u32, f);
  return (u + 0x7FFFu + ((u >> 16) & 1u)) >> 16;
}
__device__ __forceinline__ void split2(float v, u32& hi, u32& lo) {
  hi = f2bf(v);
  lo = f2bf(v - __builtin_bit_cast(float, hi << 16));
}
__device__ __forceinline__ float bf2f(u32 bits16) {
  return __builtin_bit_cast(float, bits16 << 16);
}

// Activation layouts:
//  smpl tower: ONE bf16 plane  [granule][PPT px][8 ch]
//  cate tower: TWO bf16 planes (hi, lo), lo at +rows*PPT*8
//  bufA (build output): dual-plane (36 rows per plane); smpl reads hi only.

// ---------------------------------------------------------------------------
// Weight prep: fp32 [Cout][Cin][TAPS] -> MFMA A-frag layout, hi/lo planes.
// ks = cb*TAPS + tap. elem = ((((coT*KS+ks)*2+f)*2+wco)*64+lane)*8+j
// co = coT*64+wco*32+f*16+(lane&15); ci = cb*32+(lane>>4)*8+j
// ---------------------------------------------------------------------------
struct PrepDesc {
  const float* src[9];
  int Cin[9];
  int Cout[9];
  int CB[9];
  int TAPS[9];
  int nCoT[9];
  int dstOff[9];
};

__global__ __launch_bounds__(256) void prep_weights(PrepDesc pd, u16* __restrict__ wHi,
                                                    u16* __restrict__ wLo) {
  int cfg = blockIdx.y;
  int CB = pd.CB[cfg];
  int TAPS = pd.TAPS[cfg];
  int KS = CB * TAPS;
  int total = KS * 2048 * pd.nCoT[cfg];
  int didx = blockIdx.x * 256 + threadIdx.x;
  if (didx >= total) return;
  int j = didx & 7;
  int lane = (didx >> 3) & 63;
  int wco = (didx >> 9) & 1;
  int f = (didx >> 10) & 1;
  int rest = didx >> 11;
  int ks = rest % KS;
  int coT = rest / KS;
  int cb = ks / TAPS;
  int tap = ks - cb * TAPS;
  int ci = cb * 32 + ((lane >> 4) << 3) + j;
  int co = coT * 64 + wco * 32 + f * 16 + (lane & 15);
  float v = 0.f;
  if (ci < pd.Cin[cfg] && co < pd.Cout[cfg])
    v = pd.src[cfg][((size_t)co * pd.Cin[cfg] + ci) * TAPS + tap];
  u32 hi, lo;
  split2(v, hi, lo);
  wHi[pd.dstOff[cfg] + didx] = (u16)hi;
  wLo[pd.dstOff[cfg] + didx] = (u16)lo;
}

// ---------------------------------------------------------------------------
// halo ring zero: N granule-rows from base (covers Bs,Cs single + Bc,Cc dual)
// ---------------------------------------------------------------------------
struct ZeroDesc {
  int padOff[NLEV];
  int g[NLEV];
};

__global__ __launch_bounds__(256) void halo_zero(u16* __restrict__ base, ZeroDesc zd) {
  int px = blockIdx.x * 256 + threadIdx.x;
  if (px >= PPT) return;
  int l = 0;
#pragma unroll
  for (int i = 1; i < NLEV; i++)
    if (px >= zd.padOff[i]) l = i;
  int g = zd.g[l], gp2 = g + 2, hp2 = gp2 * gp2;
  int local = px - zd.padOff[l];
  int b = local / hp2;
  int rem = local - b * hp2;
  int yy = rem / gp2, xx = rem - yy * gp2;
  if (yy >= 1 && yy <= g && xx >= 1 && xx <= g) return;  // interior
  int r = blockIdx.y;
  uint4 z = {0u, 0u, 0u, 0u};
  *(uint4*)(base + ((size_t)r * PPT + px) * 8) = z;  // 8 u16 = 16B
}

// ---------------------------------------------------------------------------
// build: resize (optionally fused double resize) + coord ramps -> dual planes
// ---------------------------------------------------------------------------
struct BuildDesc {
  const float* src[NLEV];
  int H[NLEV];
  int mid[NLEV];
  int P[NLEV];
  int g[NLEV];
  int padOff[NLEV];
};

__device__ __forceinline__ float bsample(const float* __restrict__ pl, int H, int W,
                                         float fy, float fx) {
  int y0 = (int)floorf(fy);
  int y1 = min(y0 + 1, H - 1);
  float wy = fy - (float)y0;
  int x0 = (int)floorf(fx);
  int x1 = min(x0 + 1, W - 1);
  float wx = fx - (float)x0;
  const float* r0 = pl + (size_t)y0 * W;
  const float* r1 = pl + (size_t)y1 * W;
  float top = r0[x0] * (1.f - wx) + r0[x1] * wx;
  float bot = r1[x0] * (1.f - wx) + r1[x1] * wx;
  return top * (1.f - wy) + bot * wy;
}

__global__ __launch_bounds__(256) void build_all(BuildDesc bd, u16* __restrict__ dst) {
  int l = blockIdx.y;
  int P = bd.P[l];
  int g = bd.g[l];
  int total = 258 * P;
  int idx = blockIdx.x * 256 + threadIdx.x;
  if (idx >= total) return;
  int c = idx / P;
  int p = idx - c * P;
  int gg = g * g;
  int b = p / gg;
  int pr = p - b * gg;
  int i = pr / g;
  int j = pr - i * g;
  float val;
  if (c >= 256) {
    int tt = (c == 256) ? j : i;
    val = -1.f + 2.f * (float)tt / (float)(g - 1);
  } else {
    int H = bd.H[l], W = bd.H[l];
    int mid = bd.mid[l];
    const float* pl = bd.src[l] + ((size_t)b * 256 + c) * H * W;
    if (!mid) {
      float fy = (float)i * (float)(H - 1) / (float)(g - 1);
      float fx = (float)j * (float)(W - 1) / (float)(g - 1);
      val = bsample(pl, H, W, fy, fx);
    } else {
      int midh = mid, midw = mid;
      float fym = (float)i * (float)(midh - 1) / (float)(g - 1);
      float fxm = (float)j * (float)(midw - 1) / (float)(g - 1);
      int y0 = (int)floorf(fym);
      int y1 = min(y0 + 1, midh - 1);
      float wy = fym - (float)y0;
      int x0 = (int)floorf(fxm);
      int x1 = min(x0 + 1, midw - 1);
      float wx = fxm - (float)x0;
      float sy0 = (float)y0 * (float)(H - 1) / (float)(midh - 1);
      float sy1 = (float)y1 * (float)(H - 1) / (float)(midh - 1);
      float sx0 = (float)x0 * (float)(W - 1) / (float)(midw - 1);
      float sx1 = (float)x1 * (float)(W - 1) / (float)(midw - 1);
      float v00 = bsample(pl, H, W, sy0, sx0);
      float v01 = bsample(pl, H, W, sy0, sx1);
      float v10 = bsample(pl, H, W, sy1, sx0);
      float v11 = bsample(pl, H, W, sy1, sx1);
      float top = v00 * (1.f - wx) + v01 * wx;
      float bot = v10 * (1.f - wx) + v11 * wx;
      val = top * (1.f - wy) + bot * wy;
    }
  }
  int gp2 = g + 2;
  int hpos = bd.padOff[l] + b * gp2 * gp2 + (i + 1) * gp2 + (j + 1);
  u32 hi, lo;
  split2(val, hi, lo);
  size_t base = ((size_t)(c >> 3) * PPT + hpos) * 8 + (c & 7);
  dst[base] = (u16)hi;
  dst[(size_t)36 * PPT * 8 + base] = (u16)lo;
}

// ---------------------------------------------------------------------------
// MFMA conv 3x3 v10: v7 + s_setprio around per-tap MFMA cluster (T5).
//   smpl (tower 0): single-plane acts, 2-MFMA/MAC
//   cate (tower 1): dual-plane acts, 3-MFMA/MAC
// DMA-staged double-buffered LDS halo via global_load_lds.
// ---------------------------------------------------------------------------
struct ConvDesc {
  int tS[NLEV + 1];  // cumulative 128-px tiles
  int padOff[NLEV];
  int g[NLEV];
  int P[NLEV];
};

__global__ __launch_bounds__(256) void conv_mfma(
    const u16* __restrict__ inS, const u16* __restrict__ inC, int inCRows,
    const u16* __restrict__ wHiB, const u16* __restrict__ wLoB, int wOffS,
    int wOffC, const float* __restrict__ bS, const float* __restrict__ bC,
    u16* __restrict__ outS, u16* __restrict__ outC, ConvDesc d, int CBS, int CBC) {
  const int bid = blockIdx.x;
  const int xcd = bid & 7;
  const int i6 = bid >> 3;  // 0..127
  const int tower = i6 & 1;
  const int coT = (i6 >> 1) & 3;
  const int tile = xcd + (i6 >> 3) * 8;
  if (tile >= d.tS[NLEV]) return;

  const bool dual = (tower != 0);
  const u16* __restrict__ inHi = tower ? inC : inS;
  const u16* __restrict__ inLo = inHi + (size_t)inCRows * PPT * 8;  // dual only
  u16* __restrict__ outHi = tower ? outC : outS;
  u16* __restrict__ outLo = outHi + (size_t)32 * PPT * 8;  // dual only
  const u16* __restrict__ wH = wHiB + (tower ? wOffC : wOffS);
  const u16* __restrict__ wL = wLoB + (tower ? wOffC : wOffS);
  const float* __restrict__ bias = tower ? bC : bS;
  const int CB = tower ? CBC : CBS;
  const int KS = CB * 9;

  int l = 0;
#pragma unroll
  for (int i = 1; i < NLEV; i++)
    if (tile >= d.tS[i]) l = i;
  const int g = d.g[l];
  const int gp2 = g + 2, hp2 = gp2 * gp2, gg = g * g;
  const int padOff = d.padOff[l];
  const int Pl = d.P[l];
  const int ptile = (tile - d.tS[l]) * 128;

  const int t = threadIdx.x;
  const int lane = t & 63;
  const int wv = t >> 6;
  const int wco = wv & 1, wp = wv >> 1;
  const int kb = lane >> 4;
  const int sgr = wv;  // staging granule index (wave-uniform)

  int h0;
  {
    int b0 = ptile / gg, pr0 = ptile - b0 * gg;
    int y0 = pr0 / g, x0 = pr0 - y0 * g;
    h0 = padOff + b0 * hp2 + (y0 + 1) * gp2 + (x0 + 1) - gp2 - 1;
  }

  int hRel[4], ob[4];
  bool vst[4];
#pragma unroll
  for (int fi = 0; fi < 4; fi++) {
    int pb = ptile + wp * 64 + fi * 16;
    vst[fi] = pb < Pl;
    int pf = pb + (lane & 15);
    if (pf >= Pl) pf = Pl - 1;
    int b = pf / gg, pr = pf - b * gg;
    int y = pr / g, x = pr - y * g;
    int h = padOff + b * hp2 + (y + 1) * gp2 + (x + 1);
    hRel[fi] = h - h0;
    ob[fi] = h;
  }

  // [dbuf][granule][plane][px][8ch] u16 -> 2*4*2*320*8*2B = 81920 B
  __shared__ u16 halo[2 * 4 * 2 * HPX * 8];

  f32x4 acc[2][4];
#pragma unroll
  for (int c = 0; c < 2; c++)
#pragma unroll
    for (int fi = 0; fi < 4; fi++) acc[c][fi] = (f32x4){0.f, 0.f, 0.f, 0.f};

  const size_t wbase =
      (size_t)coT * KS * 2048 + (size_t)wco * 512 + (size_t)lane * 8;
  bf16x8 ah0 = *(const bf16x8*)(wH + wbase);
  bf16x8 ah1 = *(const bf16x8*)(wH + wbase + 1024);
  bf16x8 al0 = *(const bf16x8*)(wL + wbase);
  bf16x8 al1 = *(const bf16x8*)(wL + wbase + 1024);

#define STAGE(dbuf, cbn)                                                          \
  {                                                                               \
    const int gr_ = (cbn)*4 + sgr;                                                \
    const u16* ghi_ = inHi + ((size_t)gr_ * PPT + h0) * 8;                        \
    u16* lb_ = halo + (size_t)(((dbuf)*4 + sgr) * 2) * (HPX * 8);                 \
    _Pragma("unroll") for (int i_ = 0; i_ < 5; i_++) {                            \
      __builtin_amdgcn_global_load_lds(                                           \
          (const __attribute__((address_space(1))) void*)(ghi_ +                  \
                                                          (size_t)(i_ * 64 + lane) * 8), \
          (__attribute__((address_space(3))) void*)(lb_ + i_ * 64 * 8), 16, 0, 0);\
    }                                                                             \
    if (dual) {                                                                   \
      const u16* glo_ = inLo + ((size_t)gr_ * PPT + h0) * 8;                      \
      _Pragma("unroll") for (int i_ = 0; i_ < 5; i_++) {                          \
        __builtin_amdgcn_global_load_lds(                                         \
            (const __attribute__((address_space(1))) void*)(glo_ +                \
                                                            (size_t)(i_ * 64 + lane) * 8), \
            (__attribute__((address_space(3))) void*)(lb_ + HPX * 8 +             \
                                                      i_ * 64 * 8),               \
            16, 0, 0);                                                            \
      }                                                                           \
    }                                                                             \
  }

  STAGE(0, 0);

  for (int cb = 0; cb < CB; ++cb) {
    const int cur = cb & 1;
    __syncthreads();  // vmcnt(0)+barrier: L(cb) landed (issued a tap-phase ago)
    if (cb + 1 < CB) STAGE(cur ^ 1, cb + 1);  // hidden under the 9-tap MFMA phase

#pragma unroll
    for (int tap = 0; tap < 9; ++tap) {
      const int ks = cb * 9 + tap;
      bf16x8 ah0n, ah1n, al0n, al1n;
      const bool have = (ks + 1) < KS;
      if (have) {
        size_t wo = wbase + (size_t)(ks + 1) * 2048;
        ah0n = *(const bf16x8*)(wH + wo);
        ah1n = *(const bf16x8*)(wH + wo + 1024);
        al0n = *(const bf16x8*)(wL + wo);
        al1n = *(const bf16x8*)(wL + wo + 1024);
      }
      const int toff = (tap / 3 - 1) * gp2 + (tap % 3) - 1;
      const u16* kbase = halo + (size_t)((cur * 4 + kb) * 2) * (HPX * 8);
      __builtin_amdgcn_s_setprio(1);  // favor MFMA-issuing wave on CU scheduler
#pragma unroll
      for (int fi = 0; fi < 4; fi++) {
        const u16* p0 = kbase + (hRel[fi] + toff) * 8;
        bf16x8 bh = *(const bf16x8*)p0;
        acc[0][fi] = MFMA16(ah0, bh, acc[0][fi], 0, 0, 0);
        acc[0][fi] = MFMA16(al0, bh, acc[0][fi], 0, 0, 0);
        acc[1][fi] = MFMA16(ah1, bh, acc[1][fi], 0, 0, 0);
        acc[1][fi] = MFMA16(al1, bh, acc[1][fi], 0, 0, 0);
        if (dual) {
          bf16x8 bl = *(const bf16x8*)(p0 + HPX * 8);
          acc[0][fi] = MFMA16(ah0, bl, acc[0][fi], 0, 0, 0);
          acc[1][fi] = MFMA16(ah1, bl, acc[1][fi], 0, 0, 0);
        }
      }
      __builtin_amdgcn_s_setprio(0);
      if (have) {
        ah0 = ah0n;
        ah1 = ah1n;
        al0 = al0n;
        al1 = al1n;
      }
    }
  }
#undef STAGE

  // epilogue: bias + relu + round/split + plane store(s)
  const int coBase = coT * 64 + wco * 32 + ((lane >> 4) << 2);
  float bAv[4], bBv[4];
#pragma unroll
  for (int i = 0; i < 4; i++) {
    bAv[i] = bias[coBase + i];
    bBv[i] = bias[coBase + 16 + i];
  }
  const size_t rowA = (size_t)(coBase >> 3) * PPT;
  const size_t rowB = (size_t)((coBase + 16) >> 3) * PPT;
  const int sub = coBase & 7;
#pragma unroll
  for (int fi = 0; fi < 4; fi++) {
    if (!vst[fi]) continue;
    if (!dual) {
      u32 h[4];
#pragma unroll
      for (int i = 0; i < 4; i++) h[i] = f2bf(fmaxf(acc[0][fi][i] + bAv[i], 0.f));
      uint2 hs = {h[0] | (h[1] << 16), h[2] | (h[3] << 16)};
      *(uint2*)(outHi + (rowA + ob[fi]) * 8 + sub) = hs;
#pragma unroll
      for (int i = 0; i < 4; i++) h[i] = f2bf(fmaxf(acc[1][fi][i] + bBv[i], 0.f));
      hs.x = h[0] | (h[1] << 16);
      hs.y = h[2] | (h[3] << 16);
      *(uint2*)(outHi + (rowB + ob[fi]) * 8 + sub) = hs;
    } else {
      u32 h[4], lo[4];
#pragma unroll
      for (int i = 0; i < 4; i++)
        split2(fmaxf(acc[0][fi][i] + bAv[i], 0.f), h[i], lo[i]);
      uint2 hs = {h[0] | (h[1] << 16), h[2] | (h[3] << 16)};
      uint2 ls = {lo[0] | (lo[1] << 16), lo[2] | (lo[3] << 16)};
      *(uint2*)(outHi + (rowA + ob[fi]) * 8 + sub) = hs;
      *(uint2*)(outLo + (rowA + ob[fi]) * 8 + sub) = ls;
#pragma unroll
      for (int i = 0; i < 4; i++)
        split2(fmaxf(acc[1][fi][i] + bBv[i], 0.f), h[i], lo[i]);
      hs.x = h[0] | (h[1] << 16);
      hs.y = h[2] | (h[3] << 16);
      ls.x = lo[0] | (lo[1] << 16);
      ls.y = lo[2] | (lo[3] << 16);
      *(uint2*)(outHi + (rowB + ob[fi]) * 8 + sub) = hs;
      *(uint2*)(outLo + (rowB + ob[fi]) * 8 + sub) = ls;
    }
  }
}

// ---------------------------------------------------------------------------
// smpl head: 1x1 conv via MFMA, single-plane acts, NHWC out.
// ---------------------------------------------------------------------------
struct HeadDesc {
  int tS64[NLEV + 1];
  int padOff[NLEV];
  int g[NLEV];
  int outOff[NLEV];
};

__global__ __launch_bounds__(256) void head1x1(
    const u16* __restrict__ actIn, const u16* __restrict__ wH,
    const u16* __restrict__ wL, const float* __restrict__ bias,
    const float* __restrict__ bias2, float* __restrict__ outB, HeadDesc d) {
  const int bx = blockIdx.x;
  const int coT = blockIdx.y;
  int l = 0;
#pragma unroll
  for (int i = 1; i < NLEV; i++)
    if (bx >= d.tS64[i]) l = i;
  const int g = d.g[l], gp2 = g + 2, hp2 = gp2 * gp2, gg = g * g;
  const int ptile = (bx - d.tS64[l]) * 64;
  const int t = threadIdx.x, lane = t & 63, wv = t >> 6;
  const int wco = wv & 1, wp = wv >> 1, kb = lane >> 4;

  int hp[2], pF[2];
#pragma unroll
  for (int fi = 0; fi < 2; fi++) {
    int pf = ptile + wp * 32 + fi * 16 + (lane & 15);
    pF[fi] = pf;
    int b = pf / gg, pr = pf - b * gg, y = pr / g, x = pr - y * g;
    hp[fi] = d.padOff[l] + b * hp2 + (y + 1) * gp2 + (x + 1);
  }
  f32x4 acc[2][2];
#pragma unroll
  for (int c = 0; c < 2; c++)
#pragma unroll
    for (int fi = 0; fi < 2; fi++) acc[c][fi] = (f32x4){0.f, 0.f, 0.f, 0.f};

  const size_t wbase = (size_t)coT * 8 * 2048 + (size_t)wco * 512 + (size_t)lane * 8;
  for (int cb = 0; cb < 8; ++cb) {
    size_t wo = wbase + (size_t)cb * 2048;
    bf16x8 ah0 = *(const bf16x8*)(wH + wo);
    bf16x8 ah1 = *(const bf16x8*)(wH + wo + 1024);
    bf16x8 al0 = *(const bf16x8*)(wL + wo);
    bf16x8 al1 = *(const bf16x8*)(wL + wo + 1024);
    const int gr = cb * 4 + kb;
#pragma unroll
    for (int fi = 0; fi < 2; fi++) {
      bf16x8 b = *(const bf16x8*)(actIn + ((size_t)gr * PPT + hp[fi]) * 8);
      acc[0][fi] = MFMA16(ah0, b, acc[0][fi], 0, 0, 0);
      acc[0][fi] = MFMA16(al0, b, acc[0][fi], 0, 0, 0);
      acc[1][fi] = MFMA16(ah1, b, acc[1][fi], 0, 0, 0);
      acc[1][fi] = MFMA16(al1, b, acc[1][fi], 0, 0, 0);
    }
  }
  const int coBase = coT * 64 + wco * 32 + ((lane >> 4) << 2);
#pragma unroll
  for (int c = 0; c < 2; c++)
#pragma unroll
    for (int fi = 0; fi < 2; fi++)
#pragma unroll
      for (int i = 0; i < 4; i++) {
        int co = coBase + c * 16 + i;
        if (co < 157)
          outB[d.outOff[l] + (size_t)pF[fi] * 157 + co] =
              acc[c][fi][i] + bias[co] + bias2[co];
      }
}

// ---------------------------------------------------------------------------
// cate head: 3x3 conv Cout=1 + sigmoid; dual-plane reads.
// ---------------------------------------------------------------------------
struct CHDesc {
  int tS64[NLEV + 1];
  int padOff[NLEV];
  int g[NLEV];
  int outOff[NLEV];
};

__global__ __launch_bounds__(256) void cate_head_all(
    const u16* __restrict__ inHi, const u16* __restrict__ inLo,
    const float* __restrict__ w, const float* __restrict__ bias,
    float* __restrict__ heat, CHDesc d) {
  int tile = blockIdx.x;
  int l = 0;
#pragma unroll
  for (int i = 1; i < NLEV; i++)
    if (tile >= d.tS64[i]) l = i;
  const int g = d.g[l];
  const int gp2 = g + 2, hp2 = gp2 * gp2, gg = g * g;
  const int t = threadIdx.x;
  const int ps = t & 63;
  const int cw = t >> 6;
  const int ptile = (tile - d.tS64[l]) * 64;
  int p = ptile + ps;
  int b = p / gg, pr = p - b * gg, y = pr / g, x = pr - y * g;
  const int hbase = d.padOff[l] + b * hp2 + (y + 1) * gp2 + (x + 1);

  __shared__ float ws[32][9][8];
  for (int i = t; i < 2304; i += 256) {
    int ci = i / 9, tap = i - ci * 9;
    ws[ci >> 3][tap][ci & 7] = w[i];
  }
  __syncthreads();

  float s = 0.f;
  for (int gr = cw; gr < 32; gr += 4) {
    const u16* ph = inHi + ((size_t)gr * PPT + hbase) * 8;
    const u16* pl = inLo + ((size_t)gr * PPT + hbase) * 8;
#pragma unroll
    for (int tap = 0; tap < 9; tap++) {
      const int toff = (tap / 3 - 1) * gp2 + (tap % 3) - 1;
      uint4 hq = *(const uint4*)(ph + (ptrdiff_t)toff * 8);
      uint4 lq = *(const uint4*)(pl + (ptrdiff_t)toff * 8);
      const float* wp = ws[gr][tap];
      s += (bf2f(hq.x & 0xFFFFu) + bf2f(lq.x & 0xFFFFu)) * wp[0] +
           (bf2f(hq.x >> 16) + bf2f(lq.x >> 16)) * wp[1] +
           (bf2f(hq.y & 0xFFFFu) + bf2f(lq.y & 0xFFFFu)) * wp[2] +
           (bf2f(hq.y >> 16) + bf2f(lq.y >> 16)) * wp[3] +
           (bf2f(hq.z & 0xFFFFu) + bf2f(lq.z & 0xFFFFu)) * wp[4] +
           (bf2f(hq.z >> 16) + bf2f(lq.z >> 16)) * wp[5] +
           (bf2f(hq.w & 0xFFFFu) + bf2f(lq.w & 0xFFFFu)) * wp[6] +
           (bf2f(hq.w >> 16) + bf2f(lq.w >> 16)) * wp[7];
    }
  }
  __shared__ float red[4][64];
  red[cw][ps] = s;
  __syncthreads();
  if (cw == 0) {
    float tot = bias[0] + red[0][ps] + red[1][ps] + red[2][ps] + red[3][ps];
    heat[d.outOff[l] + p] = 1.f / (1.f + expf(-tot));
  }
}

// points_nms * heat, flat heat in (cumP offsets), NHWC (C=1) out.
struct SmallDesc {
  int P[NLEV];
  int g[NLEV];
  int inOff[NLEV];
  int outOff[NLEV];
};

__global__ void nms_all(const float* __restrict__ heat, float* __restrict__ out,
                        SmallDesc d) {
  int l = blockIdx.y;
  int P = d.P[l], g = d.g[l];
  int gg = g * g;
  int p = blockIdx.x * 256 + threadIdx.x;
  if (p >= P) return;
  int pr = p % gg;
  int y = pr / g;
  int x = pr - y * g;
  const float* hb = heat + d.inOff[l];
  float c = hb[p], m = c;
  if (y > 0) {
    m = fmaxf(m, hb[p - g]);
    if (x > 0) m = fmaxf(m, hb[p - g - 1]);
  }
  if (x > 0) m = fmaxf(m, hb[p - 1]);
  out[d.outOff[l] + p] = (m == c) ? c : 0.f;
}

// ---------------------------------------------------------------------------
extern "C" void kernel_launch(void* const* d_in, const int* in_sizes, int n_in,
                              void* d_out, int out_size, void* d_ws, size_t ws_size,
                              hipStream_t stream) {
  const float* feat[5];
  for (int i = 0; i < 5; i++) feat[i] = (const float*)d_in[i];
  const float* smpl_w0 = (const float*)d_in[5];
  const float* smpl_b0 = (const float*)d_in[6];
  const float* smpl_w = (const float*)d_in[7];
  const float* smpl_b = (const float*)d_in[8];
  const float* cate_w0 = (const float*)d_in[9];
  const float* cate_b0 = (const float*)d_in[10];
  const float* cate_w = (const float*)d_in[11];
  const float* cate_b = (const float*)d_in[12];
  const float* cate_head_w = (const float*)d_in[13];
  const float* cate_head_b = (const float*)d_in[14];
  const float* smpl_head_w = (const float*)d_in[15];
  const float* smpl_head_b = (const float*)d_in[16];
  const float* smpl_init = (const float*)d_in[17];
  float* out = (float*)d_out;

  static const int GR[5] = {40, 36, 24, 16, 12};
  static const int SH[5] = {200, 100, 50, 25, 13};
  static const int MIDW[5] = {100, 0, 0, 0, 25};

  int P[5], cumP[6], tS64[6], tS128[6], padOff[5];
  cumP[0] = 0;
  tS64[0] = 0;
  tS128[0] = 0;
  int po = 0;
  for (int l = 0; l < 5; l++) {
    P[l] = 4 * GR[l] * GR[l];
    cumP[l + 1] = cumP[l] + P[l];
    tS64[l + 1] = tS64[l] + P[l] / 64;
    tS128[l + 1] = tS128[l] + (P[l] + 127) / 128;
    padOff[l] = po;
    po += 4 * (GR[l] + 2) * (GR[l] + 2);
  }

  int smpl_off[5], cate_off[5];
  {
    int off = 0;
    for (int l = 0; l < 5; l++) {
      smpl_off[l] = off;
      off += P[l] * 157;
    }
    for (int l = 0; l < 5; l++) {
      cate_off[l] = off;
      off += P[l];
    }
  }

  // workspace (u16 units):
  //   bufA dual (72 rows) | Bs (32) | Cs (32) | Bc dual (64) | Cc dual (64)
  u16* bufA = (u16*)d_ws;
  u16* bufBs = bufA + (size_t)72 * PPT * 8;
  u16* bufCs = bufBs + (size_t)32 * PPT * 8;
  u16* bufBc = bufCs + (size_t)32 * PPT * 8;
  u16* bufCc = bufBc + (size_t)64 * PPT * 8;
  float* heat = (float*)(bufCc + (size_t)64 * PPT * 8);
  u16* wHi = (u16*)(heat + 15488);

  // weight prep configs
  PrepDesc pd;
  const size_t LSTR = (size_t)256 * 256 * 9;
  pd.src[0] = smpl_w0;
  pd.src[1] = smpl_w;
  pd.src[2] = smpl_w + LSTR;
  pd.src[3] = smpl_w + 2 * LSTR;
  pd.src[4] = cate_w0;
  pd.src[5] = cate_w;
  pd.src[6] = cate_w + LSTR;
  pd.src[7] = cate_w + 2 * LSTR;
  pd.src[8] = smpl_head_w;
  for (int i = 0; i < 9; i++) {
    pd.Cin[i] = 256;
    pd.Cout[i] = 256;
    pd.CB[i] = 8;
    pd.TAPS[i] = 9;
    pd.nCoT[i] = 4;
  }
  pd.Cin[0] = 258;
  pd.CB[0] = 9;
  pd.Cout[8] = 157;
  pd.TAPS[8] = 1;
  pd.nCoT[8] = 3;
  size_t WTOT = 0;
  for (int i = 0; i < 9; i++) {
    pd.dstOff[i] = (int)WTOT;
    WTOT += (size_t)pd.CB[i] * pd.TAPS[i] * 2048 * pd.nCoT[i];
  }
  u16* wLo = wHi + WTOT;

  // zero bufA (both planes incl pad granules + rings); ring-zero tower buffers
  hipMemsetAsync(bufA, 0, (size_t)72 * PPT * 16, stream);
  ZeroDesc zd;
  for (int l = 0; l < 5; l++) {
    zd.padOff[l] = padOff[l];
    zd.g[l] = GR[l];
  }
  // 192 contiguous granule-rows: Bs(32) + Cs(32) + Bc(64) + Cc(64)
  hipLaunchKernelGGL(halo_zero, dim3((PPT + 255) / 256, 192), dim3(256), 0, stream,
                     bufBs, zd);

  hipLaunchKernelGGL(prep_weights, dim3(2592, 9), dim3(256), 0, stream, pd, wHi, wLo);

  // build inputs (dual-plane into bufA)
  BuildDesc bd;
  for (int l = 0; l < 5; l++) {
    bd.src[l] = feat[l];
    bd.H[l] = SH[l];
    bd.mid[l] = MIDW[l];
    bd.P[l] = P[l];
    bd.g[l] = GR[l];
    bd.padOff[l] = padOff[l];
  }
  hipLaunchKernelGGL(build_all, dim3((258 * P[0] + 255) / 256, 5), dim3(256), 0,
                     stream, bd, bufA);

  ConvDesc cd;
  HeadDesc hd;
  CHDesc chd;
  SmallDesc nd;
  for (int i = 0; i <= 5; i++) {
    cd.tS[i] = tS128[i];
    hd.tS64[i] = tS64[i];
    chd.tS64[i] = tS64[i];
  }
  for (int l = 0; l < 5; l++) {
    cd.padOff[l] = padOff[l];
    cd.g[l] = GR[l];
    cd.P[l] = P[l];
    hd.padOff[l] = padOff[l];
    hd.g[l] = GR[l];
    hd.outOff[l] = smpl_off[l];
    chd.padOff[l] = padOff[l];
    chd.g[l] = GR[l];
    chd.outOff[l] = cumP[l];
    nd.P[l] = P[l];
    nd.g[l] = GR[l];
    nd.inOff[l] = cumP[l];
    nd.outOff[l] = cate_off[l];
  }

  const int NT64 = tS64[5];   // 242
  const int CGRID = 8 * 128;  // 1024 blocks
  // merged tower conv stages (smpl single-plane, cate dual-plane)
  hipLaunchKernelGGL(conv_mfma, dim3(CGRID), dim3(256), 0, stream, bufA, bufA, 36,
                     wHi, wLo, pd.dstOff[0], pd.dstOff[4], smpl_b0, cate_b0, bufBs,
                     bufBc, cd, 9, 8);
  hipLaunchKernelGGL(conv_mfma, dim3(CGRID), dim3(256), 0, stream, bufBs, bufBc, 32,
                     wHi, wLo, pd.dstOff[1], pd.dstOff[5], smpl_b + 0, cate_b + 0,
                     bufCs, bufCc, cd, 8, 8);
  hipLaunchKernelGGL(conv_mfma, dim3(CGRID), dim3(256), 0, stream, bufCs, bufCc, 32,
                     wHi, wLo, pd.dstOff[2], pd.dstOff[6], smpl_b + 256,
                     cate_b + 256, bufBs, bufBc, cd, 8, 8);
  hipLaunchKernelGGL(conv_mfma, dim3(CGRID), dim3(256), 0, stream, bufBs, bufBc, 32,
                     wHi, wLo, pd.dstOff[3], pd.dstOff[7], smpl_b + 512,
                     cate_b + 512, bufCs, bufCc, cd, 8, 8);
  // heads
  hipLaunchKernelGGL(head1x1, dim3(NT64, 3), dim3(256), 0, stream, bufCs,
                     wHi + pd.dstOff[8], wLo + pd.dstOff[8], smpl_head_b, smpl_init,
                     out, hd);
  hipLaunchKernelGGL(cate_head_all, dim3(NT64), dim3(256), 0, stream, bufCc,
                     bufCc + (size_t)32 * PPT * 8, cate_head_w, cate_head_b, heat,
                     chd);
  hipLaunchKernelGGL(nms_all, dim3((P[0] + 255) / 256, 5), dim3(256), 0, stream,
                     heat, out, nd);
  (void)in_sizes;
  (void)n_in;
  (void)out_size;
  (void)ws_size;
}

// Round 18
// 494.019 us; speedup vs baseline: 1.8417x; 1.0098x over previous
//
#include <hip/hip_runtime.h>
#include <math.h>
#include <stdint.h>

#define NLEV 5
#define PPT 17616  // sum over levels of 4*(g+2)^2
#define HPX 320    // staged halo window (max needed span <= 306)

typedef __attribute__((ext_vector_type(8))) __bf16 bf16x8;
typedef __attribute__((ext_vector_type(4))) float f32x4;
typedef unsigned int u32;
typedef unsigned short u16;

#define MFMA16 __builtin_amdgcn_mfma_f32_16x16x32_bf16

__device__ __forceinline__ u32 f2bf(float f) {
  u32 u = __builtin_bit_cast(u32, f);
  return (u + 0x7FFFu + ((u >> 16) & 1u)) >> 16;
}
__device__ __forceinline__ void split2(float v, u32& hi, u32& lo) {
  hi = f2bf(v);
  lo = f2bf(v - __builtin_bit_cast(float, hi << 16));
}
__device__ __forceinline__ float bf2f(u32 bits16) {
  return __builtin_bit_cast(float, bits16 << 16);
}

// Activation layouts:
//  smpl tower: ONE bf16 plane  [granule][PPT px][8 ch]; weights hi-plane only
//  cate tower: TWO bf16 planes (hi, lo); weights hi+lo (3-MFMA split)
//  bufA (build output): dual-plane (36 rows per plane); smpl reads hi only.

// ---------------------------------------------------------------------------
// Weight prep: fp32 [Cout][Cin][TAPS] -> MFMA A-frag layout, hi/lo planes.
// ks = cb*TAPS + tap. elem = ((((coT*KS+ks)*2+f)*2+wco)*64+lane)*8+j
// co = coT*64+wco*32+f*16+(lane&15); ci = cb*32+(lane>>4)*8+j
// ---------------------------------------------------------------------------
struct PrepDesc {
  const float* src[9];
  int Cin[9];
  int Cout[9];
  int CB[9];
  int TAPS[9];
  int nCoT[9];
  int dstOff[9];
};

__global__ __launch_bounds__(256) void prep_weights(PrepDesc pd, u16* __restrict__ wHi,
                                                    u16* __restrict__ wLo) {
  int cfg = blockIdx.y;
  int CB = pd.CB[cfg];
  int TAPS = pd.TAPS[cfg];
  int KS = CB * TAPS;
  int total = KS * 2048 * pd.nCoT[cfg];
  int didx = blockIdx.x * 256 + threadIdx.x;
  if (didx >= total) return;
  int j = didx & 7;
  int lane = (didx >> 3) & 63;
  int wco = (didx >> 9) & 1;
  int f = (didx >> 10) & 1;
  int rest = didx >> 11;
  int ks = rest % KS;
  int coT = rest / KS;
  int cb = ks / TAPS;
  int tap = ks - cb * TAPS;
  int ci = cb * 32 + ((lane >> 4) << 3) + j;
  int co = coT * 64 + wco * 32 + f * 16 + (lane & 15);
  float v = 0.f;
  if (ci < pd.Cin[cfg] && co < pd.Cout[cfg])
    v = pd.src[cfg][((size_t)co * pd.Cin[cfg] + ci) * TAPS + tap];
  u32 hi, lo;
  split2(v, hi, lo);
  wHi[pd.dstOff[cfg] + didx] = (u16)hi;
  wLo[pd.dstOff[cfg] + didx] = (u16)lo;
}

// ---------------------------------------------------------------------------
// halo ring zero: N granule-rows from base (covers Bs,Cs single + Bc,Cc dual)
// ---------------------------------------------------------------------------
struct ZeroDesc {
  int padOff[NLEV];
  int g[NLEV];
};

__global__ __launch_bounds__(256) void halo_zero(u16* __restrict__ base, ZeroDesc zd) {
  int px = blockIdx.x * 256 + threadIdx.x;
  if (px >= PPT) return;
  int l = 0;
#pragma unroll
  for (int i = 1; i < NLEV; i++)
    if (px >= zd.padOff[i]) l = i;
  int g = zd.g[l], gp2 = g + 2, hp2 = gp2 * gp2;
  int local = px - zd.padOff[l];
  int b = local / hp2;
  int rem = local - b * hp2;
  int yy = rem / gp2, xx = rem - yy * gp2;
  if (yy >= 1 && yy <= g && xx >= 1 && xx <= g) return;  // interior
  int r = blockIdx.y;
  uint4 z = {0u, 0u, 0u, 0u};
  *(uint4*)(base + ((size_t)r * PPT + px) * 8) = z;  // 8 u16 = 16B
}

// ---------------------------------------------------------------------------
// build: resize (optionally fused double resize) + coord ramps -> dual planes
// ---------------------------------------------------------------------------
struct BuildDesc {
  const float* src[NLEV];
  int H[NLEV];
  int mid[NLEV];
  int P[NLEV];
  int g[NLEV];
  int padOff[NLEV];
};

__device__ __forceinline__ float bsample(const float* __restrict__ pl, int H, int W,
                                         float fy, float fx) {
  int y0 = (int)floorf(fy);
  int y1 = min(y0 + 1, H - 1);
  float wy = fy - (float)y0;
  int x0 = (int)floorf(fx);
  int x1 = min(x0 + 1, W - 1);
  float wx = fx - (float)x0;
  const float* r0 = pl + (size_t)y0 * W;
  const float* r1 = pl + (size_t)y1 * W;
  float top = r0[x0] * (1.f - wx) + r0[x1] * wx;
  float bot = r1[x0] * (1.f - wx) + r1[x1] * wx;
  return top * (1.f - wy) + bot * wy;
}

__global__ __launch_bounds__(256) void build_all(BuildDesc bd, u16* __restrict__ dst) {
  int l = blockIdx.y;
  int P = bd.P[l];
  int g = bd.g[l];
  int total = 258 * P;
  int idx = blockIdx.x * 256 + threadIdx.x;
  if (idx >= total) return;
  int c = idx / P;
  int p = idx - c * P;
  int gg = g * g;
  int b = p / gg;
  int pr = p - b * gg;
  int i = pr / g;
  int j = pr - i * g;
  float val;
  if (c >= 256) {
    int tt = (c == 256) ? j : i;
    val = -1.f + 2.f * (float)tt / (float)(g - 1);
  } else {
    int H = bd.H[l], W = bd.H[l];
    int mid = bd.mid[l];
    const float* pl = bd.src[l] + ((size_t)b * 256 + c) * H * W;
    if (!mid) {
      float fy = (float)i * (float)(H - 1) / (float)(g - 1);
      float fx = (float)j * (float)(W - 1) / (float)(g - 1);
      val = bsample(pl, H, W, fy, fx);
    } else {
      int midh = mid, midw = mid;
      float fym = (float)i * (float)(midh - 1) / (float)(g - 1);
      float fxm = (float)j * (float)(midw - 1) / (float)(g - 1);
      int y0 = (int)floorf(fym);
      int y1 = min(y0 + 1, midh - 1);
      float wy = fym - (float)y0;
      int x0 = (int)floorf(fxm);
      int x1 = min(x0 + 1, midw - 1);
      float wx = fxm - (float)x0;
      float sy0 = (float)y0 * (float)(H - 1) / (float)(midh - 1);
      float sy1 = (float)y1 * (float)(H - 1) / (float)(midh - 1);
      float sx0 = (float)x0 * (float)(W - 1) / (float)(midw - 1);
      float sx1 = (float)x1 * (float)(W - 1) / (float)(midw - 1);
      float v00 = bsample(pl, H, W, sy0, sx0);
      float v01 = bsample(pl, H, W, sy0, sx1);
      float v10 = bsample(pl, H, W, sy1, sx0);
      float v11 = bsample(pl, H, W, sy1, sx1);
      float top = v00 * (1.f - wx) + v01 * wx;
      float bot = v10 * (1.f - wx) + v11 * wx;
      val = top * (1.f - wy) + bot * wy;
    }
  }
  int gp2 = g + 2;
  int hpos = bd.padOff[l] + b * gp2 * gp2 + (i + 1) * gp2 + (j + 1);
  u32 hi, lo;
  split2(val, hi, lo);
  size_t base = ((size_t)(c >> 3) * PPT + hpos) * 8 + (c & 7);
  dst[base] = (u16)hi;
  dst[(size_t)36 * PPT * 8 + base] = (u16)lo;
}

// ---------------------------------------------------------------------------
// MFMA conv 3x3 v11: v10 + smpl tower uses hi-plane weights only (2 MFMA/tap/fi).
//   smpl (tower 0): bf16 acts x bf16 weights (2 MFMA/fi)
//   cate (tower 1): dual-plane acts, split weights (6 MFMA/fi)
// DMA-staged double-buffered LDS halo via global_load_lds. setprio on MFMA.
// ---------------------------------------------------------------------------
struct ConvDesc {
  int tS[NLEV + 1];  // cumulative 128-px tiles
  int padOff[NLEV];
  int g[NLEV];
  int P[NLEV];
};

__global__ __launch_bounds__(256) void conv_mfma(
    const u16* __restrict__ inS, const u16* __restrict__ inC, int inCRows,
    const u16* __restrict__ wHiB, const u16* __restrict__ wLoB, int wOffS,
    int wOffC, const float* __restrict__ bS, const float* __restrict__ bC,
    u16* __restrict__ outS, u16* __restrict__ outC, ConvDesc d, int CBS, int CBC) {
  const int bid = blockIdx.x;
  const int xcd = bid & 7;
  const int i6 = bid >> 3;  // 0..127
  const int tower = i6 & 1;
  const int coT = (i6 >> 1) & 3;
  const int tile = xcd + (i6 >> 3) * 8;
  if (tile >= d.tS[NLEV]) return;

  const bool dual = (tower != 0);
  const u16* __restrict__ inHi = tower ? inC : inS;
  const u16* __restrict__ inLo = inHi + (size_t)inCRows * PPT * 8;  // dual only
  u16* __restrict__ outHi = tower ? outC : outS;
  u16* __restrict__ outLo = outHi + (size_t)32 * PPT * 8;  // dual only
  const u16* __restrict__ wH = wHiB + (tower ? wOffC : wOffS);
  const u16* __restrict__ wL = wLoB + (tower ? wOffC : wOffS);
  const float* __restrict__ bias = tower ? bC : bS;
  const int CB = tower ? CBC : CBS;
  const int KS = CB * 9;

  int l = 0;
#pragma unroll
  for (int i = 1; i < NLEV; i++)
    if (tile >= d.tS[i]) l = i;
  const int g = d.g[l];
  const int gp2 = g + 2, hp2 = gp2 * gp2, gg = g * g;
  const int padOff = d.padOff[l];
  const int Pl = d.P[l];
  const int ptile = (tile - d.tS[l]) * 128;

  const int t = threadIdx.x;
  const int lane = t & 63;
  const int wv = t >> 6;
  const int wco = wv & 1, wp = wv >> 1;
  const int kb = lane >> 4;
  const int sgr = wv;  // staging granule index (wave-uniform)

  int h0;
  {
    int b0 = ptile / gg, pr0 = ptile - b0 * gg;
    int y0 = pr0 / g, x0 = pr0 - y0 * g;
    h0 = padOff + b0 * hp2 + (y0 + 1) * gp2 + (x0 + 1) - gp2 - 1;
  }

  int hRel[4], ob[4];
  bool vst[4];
#pragma unroll
  for (int fi = 0; fi < 4; fi++) {
    int pb = ptile + wp * 64 + fi * 16;
    vst[fi] = pb < Pl;
    int pf = pb + (lane & 15);
    if (pf >= Pl) pf = Pl - 1;
    int b = pf / gg, pr = pf - b * gg;
    int y = pr / g, x = pr - y * g;
    int h = padOff + b * hp2 + (y + 1) * gp2 + (x + 1);
    hRel[fi] = h - h0;
    ob[fi] = h;
  }

  // [dbuf][granule][plane][px][8ch] u16 -> 2*4*2*320*8*2B = 81920 B
  __shared__ u16 halo[2 * 4 * 2 * HPX * 8];

  f32x4 acc[2][4];
#pragma unroll
  for (int c = 0; c < 2; c++)
#pragma unroll
    for (int fi = 0; fi < 4; fi++) acc[c][fi] = (f32x4){0.f, 0.f, 0.f, 0.f};

  const size_t wbase =
      (size_t)coT * KS * 2048 + (size_t)wco * 512 + (size_t)lane * 8;
  bf16x8 ah0 = *(const bf16x8*)(wH + wbase);
  bf16x8 ah1 = *(const bf16x8*)(wH + wbase + 1024);
  bf16x8 al0, al1;
  if (dual) {
    al0 = *(const bf16x8*)(wL + wbase);
    al1 = *(const bf16x8*)(wL + wbase + 1024);
  }

#define STAGE(dbuf, cbn)                                                          \
  {                                                                               \
    const int gr_ = (cbn)*4 + sgr;                                                \
    const u16* ghi_ = inHi + ((size_t)gr_ * PPT + h0) * 8;                        \
    u16* lb_ = halo + (size_t)(((dbuf)*4 + sgr) * 2) * (HPX * 8);                 \
    _Pragma("unroll") for (int i_ = 0; i_ < 5; i_++) {                            \
      __builtin_amdgcn_global_load_lds(                                           \
          (const __attribute__((address_space(1))) void*)(ghi_ +                  \
                                                          (size_t)(i_ * 64 + lane) * 8), \
          (__attribute__((address_space(3))) void*)(lb_ + i_ * 64 * 8), 16, 0, 0);\
    }                                                                             \
    if (dual) {                                                                   \
      const u16* glo_ = inLo + ((size_t)gr_ * PPT + h0) * 8;                      \
      _Pragma("unroll") for (int i_ = 0; i_ < 5; i_++) {                          \
        __builtin_amdgcn_global_load_lds(                                         \
            (const __attribute__((address_space(1))) void*)(glo_ +                \
                                                            (size_t)(i_ * 64 + lane) * 8), \
            (__attribute__((address_space(3))) void*)(lb_ + HPX * 8 +             \
                                                      i_ * 64 * 8),               \
            16, 0, 0);                                                            \
      }                                                                           \
    }                                                                             \
  }

  STAGE(0, 0);

  for (int cb = 0; cb < CB; ++cb) {
    const int cur = cb & 1;
    __syncthreads();  // vmcnt(0)+barrier: L(cb) landed (issued a tap-phase ago)
    if (cb + 1 < CB) STAGE(cur ^ 1, cb + 1);  // hidden under the 9-tap MFMA phase

#pragma unroll
    for (int tap = 0; tap < 9; ++tap) {
      const int ks = cb * 9 + tap;
      bf16x8 ah0n, ah1n, al0n, al1n;
      const bool have = (ks + 1) < KS;
      if (have) {
        size_t wo = wbase + (size_t)(ks + 1) * 2048;
        ah0n = *(const bf16x8*)(wH + wo);
        ah1n = *(const bf16x8*)(wH + wo + 1024);
        if (dual) {
          al0n = *(const bf16x8*)(wL + wo);
          al1n = *(const bf16x8*)(wL + wo + 1024);
        }
      }
      const int toff = (tap / 3 - 1) * gp2 + (tap % 3) - 1;
      const u16* kbase = halo + (size_t)((cur * 4 + kb) * 2) * (HPX * 8);
      __builtin_amdgcn_s_setprio(1);  // favor MFMA-issuing wave on CU scheduler
#pragma unroll
      for (int fi = 0; fi < 4; fi++) {
        const u16* p0 = kbase + (hRel[fi] + toff) * 8;
        bf16x8 bh = *(const bf16x8*)p0;
        acc[0][fi] = MFMA16(ah0, bh, acc[0][fi], 0, 0, 0);
        acc[1][fi] = MFMA16(ah1, bh, acc[1][fi], 0, 0, 0);
        if (dual) {
          bf16x8 bl = *(const bf16x8*)(p0 + HPX * 8);
          acc[0][fi] = MFMA16(al0, bh, acc[0][fi], 0, 0, 0);
          acc[1][fi] = MFMA16(al1, bh, acc[1][fi], 0, 0, 0);
          acc[0][fi] = MFMA16(ah0, bl, acc[0][fi], 0, 0, 0);
          acc[1][fi] = MFMA16(ah1, bl, acc[1][fi], 0, 0, 0);
        }
      }
      __builtin_amdgcn_s_setprio(0);
      if (have) {
        ah0 = ah0n;
        ah1 = ah1n;
        if (dual) {
          al0 = al0n;
          al1 = al1n;
        }
      }
    }
  }
#undef STAGE

  // epilogue: bias + relu + round/split + plane store(s)
  const int coBase = coT * 64 + wco * 32 + ((lane >> 4) << 2);
  float bAv[4], bBv[4];
#pragma unroll
  for (int i = 0; i < 4; i++) {
    bAv[i] = bias[coBase + i];
    bBv[i] = bias[coBase + 16 + i];
  }
  const size_t rowA = (size_t)(coBase >> 3) * PPT;
  const size_t rowB = (size_t)((coBase + 16) >> 3) * PPT;
  const int sub = coBase & 7;
#pragma unroll
  for (int fi = 0; fi < 4; fi++) {
    if (!vst[fi]) continue;
    if (!dual) {
      u32 h[4];
#pragma unroll
      for (int i = 0; i < 4; i++) h[i] = f2bf(fmaxf(acc[0][fi][i] + bAv[i], 0.f));
      uint2 hs = {h[0] | (h[1] << 16), h[2] | (h[3] << 16)};
      *(uint2*)(outHi + (rowA + ob[fi]) * 8 + sub) = hs;
#pragma unroll
      for (int i = 0; i < 4; i++) h[i] = f2bf(fmaxf(acc[1][fi][i] + bBv[i], 0.f));
      hs.x = h[0] | (h[1] << 16);
      hs.y = h[2] | (h[3] << 16);
      *(uint2*)(outHi + (rowB + ob[fi]) * 8 + sub) = hs;
    } else {
      u32 h[4], lo[4];
#pragma unroll
      for (int i = 0; i < 4; i++)
        split2(fmaxf(acc[0][fi][i] + bAv[i], 0.f), h[i], lo[i]);
      uint2 hs = {h[0] | (h[1] << 16), h[2] | (h[3] << 16)};
      uint2 ls = {lo[0] | (lo[1] << 16), lo[2] | (lo[3] << 16)};
      *(uint2*)(outHi + (rowA + ob[fi]) * 8 + sub) = hs;
      *(uint2*)(outLo + (rowA + ob[fi]) * 8 + sub) = ls;
#pragma unroll
      for (int i = 0; i < 4; i++)
        split2(fmaxf(acc[1][fi][i] + bBv[i], 0.f), h[i], lo[i]);
      hs.x = h[0] | (h[1] << 16);
      hs.y = h[2] | (h[3] << 16);
      ls.x = lo[0] | (lo[1] << 16);
      ls.y = lo[2] | (lo[3] << 16);
      *(uint2*)(outHi + (rowB + ob[fi]) * 8 + sub) = hs;
      *(uint2*)(outLo + (rowB + ob[fi]) * 8 + sub) = ls;
    }
  }
}

// ---------------------------------------------------------------------------
// smpl head: 1x1 conv via MFMA, bf16 acts x bf16 weights, NHWC out.
// ---------------------------------------------------------------------------
struct HeadDesc {
  int tS64[NLEV + 1];
  int padOff[NLEV];
  int g[NLEV];
  int outOff[NLEV];
};

__global__ __launch_bounds__(256) void head1x1(
    const u16* __restrict__ actIn, const u16* __restrict__ wH,
    const u16* __restrict__ wL, const float* __restrict__ bias,
    const float* __restrict__ bias2, float* __restrict__ outB, HeadDesc d) {
  const int bx = blockIdx.x;
  const int coT = blockIdx.y;
  int l = 0;
#pragma unroll
  for (int i = 1; i < NLEV; i++)
    if (bx >= d.tS64[i]) l = i;
  const int g = d.g[l], gp2 = g + 2, hp2 = gp2 * gp2, gg = g * g;
  const int ptile = (bx - d.tS64[l]) * 64;
  const int t = threadIdx.x, lane = t & 63, wv = t >> 6;
  const int wco = wv & 1, wp = wv >> 1, kb = lane >> 4;

  int hp[2], pF[2];
#pragma unroll
  for (int fi = 0; fi < 2; fi++) {
    int pf = ptile + wp * 32 + fi * 16 + (lane & 15);
    pF[fi] = pf;
    int b = pf / gg, pr = pf - b * gg, y = pr / g, x = pr - y * g;
    hp[fi] = d.padOff[l] + b * hp2 + (y + 1) * gp2 + (x + 1);
  }
  f32x4 acc[2][2];
#pragma unroll
  for (int c = 0; c < 2; c++)
#pragma unroll
    for (int fi = 0; fi < 2; fi++) acc[c][fi] = (f32x4){0.f, 0.f, 0.f, 0.f};

  const size_t wbase = (size_t)coT * 8 * 2048 + (size_t)wco * 512 + (size_t)lane * 8;
  for (int cb = 0; cb < 8; ++cb) {
    size_t wo = wbase + (size_t)cb * 2048;
    bf16x8 ah0 = *(const bf16x8*)(wH + wo);
    bf16x8 ah1 = *(const bf16x8*)(wH + wo + 1024);
    bf16x8 al0 = *(const bf16x8*)(wL + wo);
    bf16x8 al1 = *(const bf16x8*)(wL + wo + 1024);
    const int gr = cb * 4 + kb;
#pragma unroll
    for (int fi = 0; fi < 2; fi++) {
      bf16x8 b = *(const bf16x8*)(actIn + ((size_t)gr * PPT + hp[fi]) * 8);
      acc[0][fi] = MFMA16(ah0, b, acc[0][fi], 0, 0, 0);
      acc[0][fi] = MFMA16(al0, b, acc[0][fi], 0, 0, 0);
      acc[1][fi] = MFMA16(ah1, b, acc[1][fi], 0, 0, 0);
      acc[1][fi] = MFMA16(al1, b, acc[1][fi], 0, 0, 0);
    }
  }
  const int coBase = coT * 64 + wco * 32 + ((lane >> 4) << 2);
#pragma unroll
  for (int c = 0; c < 2; c++)
#pragma unroll
    for (int fi = 0; fi < 2; fi++)
#pragma unroll
      for (int i = 0; i < 4; i++) {
        int co = coBase + c * 16 + i;
        if (co < 157)
          outB[d.outOff[l] + (size_t)pF[fi] * 157 + co] =
              acc[c][fi][i] + bias[co] + bias2[co];
      }
}

// ---------------------------------------------------------------------------
// cate head: 3x3 conv Cout=1 + sigmoid; dual-plane reads.
// ---------------------------------------------------------------------------
struct CHDesc {
  int tS64[NLEV + 1];
  int padOff[NLEV];
  int g[NLEV];
  int outOff[NLEV];
};

__global__ __launch_bounds__(256) void cate_head_all(
    const u16* __restrict__ inHi, const u16* __restrict__ inLo,
    const float* __restrict__ w, const float* __restrict__ bias,
    float* __restrict__ heat, CHDesc d) {
  int tile = blockIdx.x;
  int l = 0;
#pragma unroll
  for (int i = 1; i < NLEV; i++)
    if (tile >= d.tS64[i]) l = i;
  const int g = d.g[l];
  const int gp2 = g + 2, hp2 = gp2 * gp2, gg = g * g;
  const int t = threadIdx.x;
  const int ps = t & 63;
  const int cw = t >> 6;
  const int ptile = (tile - d.tS64[l]) * 64;
  int p = ptile + ps;
  int b = p / gg, pr = p - b * gg, y = pr / g, x = pr - y * g;
  const int hbase = d.padOff[l] + b * hp2 + (y + 1) * gp2 + (x + 1);

  __shared__ float ws[32][9][8];
  for (int i = t; i < 2304; i += 256) {
    int ci = i / 9, tap = i - ci * 9;
    ws[ci >> 3][tap][ci & 7] = w[i];
  }
  __syncthreads();

  float s = 0.f;
  for (int gr = cw; gr < 32; gr += 4) {
    const u16* ph = inHi + ((size_t)gr * PPT + hbase) * 8;
    const u16* pl = inLo + ((size_t)gr * PPT + hbase) * 8;
#pragma unroll
    for (int tap = 0; tap < 9; tap++) {
      const int toff = (tap / 3 - 1) * gp2 + (tap % 3) - 1;
      uint4 hq = *(const uint4*)(ph + (ptrdiff_t)toff * 8);
      uint4 lq = *(const uint4*)(pl + (ptrdiff_t)toff * 8);
      const float* wp = ws[gr][tap];
      s += (bf2f(hq.x & 0xFFFFu) + bf2f(lq.x & 0xFFFFu)) * wp[0] +
           (bf2f(hq.x >> 16) + bf2f(lq.x >> 16)) * wp[1] +
           (bf2f(hq.y & 0xFFFFu) + bf2f(lq.y & 0xFFFFu)) * wp[2] +
           (bf2f(hq.y >> 16) + bf2f(lq.y >> 16)) * wp[3] +
           (bf2f(hq.z & 0xFFFFu) + bf2f(lq.z & 0xFFFFu)) * wp[4] +
           (bf2f(hq.z >> 16) + bf2f(lq.z >> 16)) * wp[5] +
           (bf2f(hq.w & 0xFFFFu) + bf2f(lq.w & 0xFFFFu)) * wp[6] +
           (bf2f(hq.w >> 16) + bf2f(lq.w >> 16)) * wp[7];
    }
  }
  __shared__ float red[4][64];
  red[cw][ps] = s;
  __syncthreads();
  if (cw == 0) {
    float tot = bias[0] + red[0][ps] + red[1][ps] + red[2][ps] + red[3][ps];
    heat[d.outOff[l] + p] = 1.f / (1.f + expf(-tot));
  }
}

// points_nms * heat, flat heat in (cumP offsets), NHWC (C=1) out.
struct SmallDesc {
  int P[NLEV];
  int g[NLEV];
  int inOff[NLEV];
  int outOff[NLEV];
};

__global__ void nms_all(const float* __restrict__ heat, float* __restrict__ out,
                        SmallDesc d) {
  int l = blockIdx.y;
  int P = d.P[l], g = d.g[l];
  int gg = g * g;
  int p = blockIdx.x * 256 + threadIdx.x;
  if (p >= P) return;
  int pr = p % gg;
  int y = pr / g;
  int x = pr - y * g;
  const float* hb = heat + d.inOff[l];
  float c = hb[p], m = c;
  if (y > 0) {
    m = fmaxf(m, hb[p - g]);
    if (x > 0) m = fmaxf(m, hb[p - g - 1]);
  }
  if (x > 0) m = fmaxf(m, hb[p - 1]);
  out[d.outOff[l] + p] = (m == c) ? c : 0.f;
}

// ---------------------------------------------------------------------------
extern "C" void kernel_launch(void* const* d_in, const int* in_sizes, int n_in,
                              void* d_out, int out_size, void* d_ws, size_t ws_size,
                              hipStream_t stream) {
  const float* feat[5];
  for (int i = 0; i < 5; i++) feat[i] = (const float*)d_in[i];
  const float* smpl_w0 = (const float*)d_in[5];
  const float* smpl_b0 = (const float*)d_in[6];
  const float* smpl_w = (const float*)d_in[7];
  const float* smpl_b = (const float*)d_in[8];
  const float* cate_w0 = (const float*)d_in[9];
  const float* cate_b0 = (const float*)d_in[10];
  const float* cate_w = (const float*)d_in[11];
  const float* cate_b = (const float*)d_in[12];
  const float* cate_head_w = (const float*)d_in[13];
  const float* cate_head_b = (const float*)d_in[14];
  const float* smpl_head_w = (const float*)d_in[15];
  const float* smpl_head_b = (const float*)d_in[16];
  const float* smpl_init = (const float*)d_in[17];
  float* out = (float*)d_out;

  static const int GR[5] = {40, 36, 24, 16, 12};
  static const int SH[5] = {200, 100, 50, 25, 13};
  static const int MIDW[5] = {100, 0, 0, 0, 25};

  int P[5], cumP[6], tS64[6], tS128[6], padOff[5];
  cumP[0] = 0;
  tS64[0] = 0;
  tS128[0] = 0;
  int po = 0;
  for (int l = 0; l < 5; l++) {
    P[l] = 4 * GR[l] * GR[l];
    cumP[l + 1] = cumP[l] + P[l];
    tS64[l + 1] = tS64[l] + P[l] / 64;
    tS128[l + 1] = tS128[l] + (P[l] + 127) / 128;
    padOff[l] = po;
    po += 4 * (GR[l] + 2) * (GR[l] + 2);
  }

  int smpl_off[5], cate_off[5];
  {
    int off = 0;
    for (int l = 0; l < 5; l++) {
      smpl_off[l] = off;
      off += P[l] * 157;
    }
    for (int l = 0; l < 5; l++) {
      cate_off[l] = off;
      off += P[l];
    }
  }

  // workspace (u16 units):
  //   bufA dual (72 rows) | Bs (32) | Cs (32) | Bc dual (64) | Cc dual (64)
  u16* bufA = (u16*)d_ws;
  u16* bufBs = bufA + (size_t)72 * PPT * 8;
  u16* bufCs = bufBs + (size_t)32 * PPT * 8;
  u16* bufBc = bufCs + (size_t)32 * PPT * 8;
  u16* bufCc = bufBc + (size_t)64 * PPT * 8;
  float* heat = (float*)(bufCc + (size_t)64 * PPT * 8);
  u16* wHi = (u16*)(heat + 15488);

  // weight prep configs
  PrepDesc pd;
  const size_t LSTR = (size_t)256 * 256 * 9;
  pd.src[0] = smpl_w0;
  pd.src[1] = smpl_w;
  pd.src[2] = smpl_w + LSTR;
  pd.src[3] = smpl_w + 2 * LSTR;
  pd.src[4] = cate_w0;
  pd.src[5] = cate_w;
  pd.src[6] = cate_w + LSTR;
  pd.src[7] = cate_w + 2 * LSTR;
  pd.src[8] = smpl_head_w;
  for (int i = 0; i < 9; i++) {
    pd.Cin[i] = 256;
    pd.Cout[i] = 256;
    pd.CB[i] = 8;
    pd.TAPS[i] = 9;
    pd.nCoT[i] = 4;
  }
  pd.Cin[0] = 258;
  pd.CB[0] = 9;
  pd.Cout[8] = 157;
  pd.TAPS[8] = 1;
  pd.nCoT[8] = 3;
  size_t WTOT = 0;
  for (int i = 0; i < 9; i++) {
    pd.dstOff[i] = (int)WTOT;
    WTOT += (size_t)pd.CB[i] * pd.TAPS[i] * 2048 * pd.nCoT[i];
  }
  u16* wLo = wHi + WTOT;

  // zero bufA (both planes incl pad granules + rings); ring-zero tower buffers
  hipMemsetAsync(bufA, 0, (size_t)72 * PPT * 16, stream);
  ZeroDesc zd;
  for (int l = 0; l < 5; l++) {
    zd.padOff[l] = padOff[l];
    zd.g[l] = GR[l];
  }
  // 192 contiguous granule-rows: Bs(32) + Cs(32) + Bc(64) + Cc(64)
  hipLaunchKernelGGL(halo_zero, dim3((PPT + 255) / 256, 192), dim3(256), 0, stream,
                     bufBs, zd);

  hipLaunchKernelGGL(prep_weights, dim3(2592, 9), dim3(256), 0, stream, pd, wHi, wLo);

  // build inputs (dual-plane into bufA)
  BuildDesc bd;
  for (int l = 0; l < 5; l++) {
    bd.src[l] = feat[l];
    bd.H[l] = SH[l];
    bd.mid[l] = MIDW[l];
    bd.P[l] = P[l];
    bd.g[l] = GR[l];
    bd.padOff[l] = padOff[l];
  }
  hipLaunchKernelGGL(build_all, dim3((258 * P[0] + 255) / 256, 5), dim3(256), 0,
                     stream, bd, bufA);

  ConvDesc cd;
  HeadDesc hd;
  CHDesc chd;
  SmallDesc nd;
  for (int i = 0; i <= 5; i++) {
    cd.tS[i] = tS128[i];
    hd.tS64[i] = tS64[i];
    chd.tS64[i] = tS64[i];
  }
  for (int l = 0; l < 5; l++) {
    cd.padOff[l] = padOff[l];
    cd.g[l] = GR[l];
    cd.P[l] = P[l];
    hd.padOff[l] = padOff[l];
    hd.g[l] = GR[l];
    hd.outOff[l] = smpl_off[l];
    chd.padOff[l] = padOff[l];
    chd.g[l] = GR[l];
    chd.outOff[l] = cumP[l];
    nd.P[l] = P[l];
    nd.g[l] = GR[l];
    nd.inOff[l] = cumP[l];
    nd.outOff[l] = cate_off[l];
  }

  const int NT64 = tS64[5];   // 242
  const int CGRID = 8 * 128;  // 1024 blocks
  // merged tower conv stages (smpl hi-only weights, cate dual-plane)
  hipLaunchKernelGGL(conv_mfma, dim3(CGRID), dim3(256), 0, stream, bufA, bufA, 36,
                     wHi, wLo, pd.dstOff[0], pd.dstOff[4], smpl_b0, cate_b0, bufBs,
                     bufBc, cd, 9, 8);
  hipLaunchKernelGGL(conv_mfma, dim3(CGRID), dim3(256), 0, stream, bufBs, bufBc, 32,
                     wHi, wLo, pd.dstOff[1], pd.dstOff[5], smpl_b + 0, cate_b + 0,
                     bufCs, bufCc, cd, 8, 8);
  hipLaunchKernelGGL(conv_mfma, dim3(CGRID), dim3(256), 0, stream, bufCs, bufCc, 32,
                     wHi, wLo, pd.dstOff[2], pd.dstOff[6], smpl_b + 256,
                     cate_b + 256, bufBs, bufBc, cd, 8, 8);
  hipLaunchKernelGGL(conv_mfma, dim3(CGRID), dim3(256), 0, stream, bufBs, bufBc, 32,
                     wHi, wLo, pd.dstOff[3], pd.dstOff[7], smpl_b + 512,
                     cate_b + 512, bufCs, bufCc, cd, 8, 8);
  // heads
  hipLaunchKernelGGL(head1x1, dim3(NT64, 3), dim3(256), 0, stream, bufCs,
                     wHi + pd.dstOff[8], wLo + pd.dstOff[8], smpl_head_b, smpl_init,
                     out, hd);
  hipLaunchKernelGGL(cate_head_all, dim3(NT64), dim3(256), 0, stream, bufCc,
                     bufCc + (size_t)32 * PPT * 8, cate_head_w, cate_head_b, heat,
                     chd);
  hipLaunchKernelGGL(nms_all, dim3((P[0] + 255) / 256, 5), dim3(256), 0, stream,
                     heat, out, nd);
  (void)in_sizes;
  (void)n_in;
  (void)out_size;
  (void)ws_size;
}